// Round 12
// baseline (760.472 us; speedup 1.0000x reference)
//
#include <hip/hip_runtime.h>
#include <hip/hip_fp16.h>

#define NN 4096
#define NM 2304
#define NC 256
#define OUT_ELEMS 2359296  // 4*256*48*48
#define MAX_IT 24

static constexpr float REG_INV = 0.1f;      // 1/REG
static constexpr float A_VAL = 1.0f / 4096.0f;
static constexpr float B_VAL = 1.0f / 2304.0f;
static constexpr float ALPHA_C = 0.001f;
static constexpr float EPS_CONV = 1e-5f;  // r9-proven: exit ~iter 21
// over-relaxation u' = u*(ut/u)^1.5 via r*sqrt(r)

typedef __attribute__((ext_vector_type(8))) short bf16x8;
typedef __attribute__((ext_vector_type(4))) float f32x4;
typedef __attribute__((ext_vector_type(2))) float f32x2;

__device__ __forceinline__ float bf2f(unsigned short h) {
  return __uint_as_float(((unsigned int)h) << 16);
}
__device__ __forceinline__ unsigned short f2bf(float f) {
  unsigned int u = __float_as_uint(f);
  unsigned int r = (u + 0x7FFFu + ((u >> 16) & 1u)) >> 16;  // RNE
  return (unsigned short)r;
}
// e5m2 encode: f32 -> f16 (RNE) -> top byte with RNE on bit 7
__device__ __forceinline__ unsigned char f2e5(float x) {
  unsigned short h = __half_as_ushort(__float2half_rn(x));
  return (unsigned char)((h + 0x7Fu + ((h >> 8) & 1u)) >> 8);
}
__device__ __forceinline__ float e52f(unsigned int hs) {
  return __half2float(__ushort_as_half((unsigned short)hs));
}
// decode 4 packed e5m2 (bf8) bytes -> 4 floats
__device__ __forceinline__ void dec4(unsigned int q, float4& o) {
#if __has_builtin(__builtin_amdgcn_cvt_pk_f32_bf8)
  f32x2 lo = __builtin_amdgcn_cvt_pk_f32_bf8((int)q, false);
  f32x2 hi = __builtin_amdgcn_cvt_pk_f32_bf8((int)q, true);
  o.x = lo[0]; o.y = lo[1]; o.z = hi[0]; o.w = hi[1];
#else
  o.x = e52f((q << 8) & 0xFF00u);
  o.y = e52f(q & 0xFF00u);
  o.z = e52f((q >> 8) & 0xFF00u);
  o.w = e52f((q >> 16) & 0xFF00u);
#endif
}
__device__ __forceinline__ float waveSum(float s) {
#pragma unroll
  for (int off = 32; off > 0; off >>= 1) s += __shfl_xor(s, off);
  return s;
}

// x2[n] = sum_c X[n][c]^2 ; one wave per row
__global__ __launch_bounds__(256) void x2_kernel(const float* __restrict__ X,
                                                 float* __restrict__ x2) {
  int wid = threadIdx.x >> 6, lane = threadIdx.x & 63;
  int row = blockIdx.x * 4 + wid;
  float4 v = *(const float4*)(X + (size_t)row * NC + lane * 4);
  float s = v.x * v.x + v.y * v.y + v.z * v.z + v.w * v.w;
  s = waveSum(s);
  if (lane == 0) x2[row] = s;
}

// y2[b][m] = sum_c H[b][c][m]^2
__global__ __launch_bounds__(256) void y2_kernel(const float* __restrict__ H,
                                                 float* __restrict__ y2) {
  int gid = blockIdx.x * 256 + threadIdx.x;  // grid 36 -> 9216
  int b = gid / NM, m = gid % NM;
  const float* p = H + (size_t)b * NC * NM + m;
  float s = 0.f;
#pragma unroll 4
  for (int c = 0; c < NC; ++c) {
    float t = p[(size_t)c * NM];
    s += t * t;
  }
  y2[gid] = s;
}

// Xbf = bf16(X); grid 1024
__global__ __launch_bounds__(256) void prep_xbf(const float* __restrict__ X,
                                                unsigned short* __restrict__ Xbf) {
  size_t i = blockIdx.x * 256 + threadIdx.x;
  float4 xv = *(const float4*)(X + i * 4);
  ushort4 o = {f2bf(xv.x), f2bf(xv.y), f2bf(xv.z), f2bf(xv.w)};
  *(ushort4*)(Xbf + i * 4) = o;
}

// HT[b][m][c] = bf16(H[b][c][m]); grid (72, 8, 4)
__global__ __launch_bounds__(256) void prep_ht(const float* __restrict__ H,
                                               unsigned short* __restrict__ HT) {
  __shared__ unsigned short tile[32][34];
  const int b = blockIdx.z;
  const int mt = blockIdx.x * 32, ct = blockIdx.y * 32;
  const int t = threadIdx.x;
#pragma unroll
  for (int p = 0; p < 4; ++p) {
    int c = ct + p * 8 + (t >> 5);
    tile[t & 31][p * 8 + (t >> 5)] = f2bf(H[((size_t)b * NC + c) * NM + mt + (t & 31)]);
  }
  __syncthreads();
#pragma unroll
  for (int p = 0; p < 4; ++p) {
    int mloc = p * 8 + (t >> 5);
    HT[((size_t)b * NM + mt + mloc) * NC + ct + (t & 31)] = tile[mloc][t & 31];
  }
}

// XuT[b][c][n] = bf16(u[n]*X[n][c]); grid (128, 8, 4)
__global__ __launch_bounds__(256) void prep_xut(const float* __restrict__ X,
                                                const float* __restrict__ uF,
                                                unsigned short* __restrict__ XuT) {
  __shared__ unsigned short tile[32][34];
  const int b = blockIdx.z;
  const int nt = blockIdx.x * 32, ct = blockIdx.y * 32;
  const int t = threadIdx.x;
#pragma unroll
  for (int p = 0; p < 4; ++p) {
    int nloc = p * 8 + (t >> 5);
    float uu = uF[b * NN + nt + nloc];
    tile[nloc][t & 31] = f2bf(uu * X[(size_t)(nt + nloc) * NC + ct + (t & 31)]);
  }
  __syncthreads();
#pragma unroll
  for (int p = 0; p < 4; ++p) {
    int cloc = p * 8 + (t >> 5);
    XuT[((size_t)b * NC + ct + cloc) * NN + nt + (t & 31)] = tile[t & 31][cloc];
  }
}

// usum slot0 = 1.0 (seed: u0 = A/1 -> identity), u slot0 = A_VAL, nc = 1
__global__ __launch_bounds__(256) void init_kernel(float* __restrict__ usum0,
                                                   float* __restrict__ u0,
                                                   int* __restrict__ nc) {
  int gid = blockIdx.x * 256 + threadIdx.x;  // grid 64 -> 16384
  usum0[gid] = 1.0f;
  u0[gid] = A_VAL;
  if (gid < 8) nc[gid] = 1;
}

// MFMA cost kernel: tile 128n x 128m, 4 waves (2x2), c-steps of 32.
// Writes ONLY KT[b][m][n] (bf16) via LDS-staged coalesced float4 stores.
__global__ __launch_bounds__(256) void cost_k_mfma(
    const unsigned short* __restrict__ Xbf, const unsigned short* __restrict__ HT,
    const float* __restrict__ x2, const float* __restrict__ y2,
    unsigned short* __restrict__ KT) {
  __shared__ __align__(16) unsigned short smem[128 * 88];
  const int b = blockIdx.z;
  const int n0 = blockIdx.x * 128, m0 = blockIdx.y * 128;
  const int t = threadIdx.x, l = t & 63, w = t >> 6;
  const int wn = (w >> 1) * 64, wm = (w & 1) * 64;
  const int fr = l & 15, fq = l >> 4;
  f32x4 zero = {0.f, 0.f, 0.f, 0.f};
  f32x4 acc[4][4];
#pragma unroll
  for (int i = 0; i < 4; ++i)
#pragma unroll
    for (int j = 0; j < 4; ++j) acc[i][j] = zero;

  for (int c0 = 0; c0 < NC; c0 += 32) {
#pragma unroll
    for (int i = 0; i < 2; ++i) {
      int idx = t + i * 256;
      int row = idx >> 2, ck = idx & 3;
      float4 av = *(const float4*)(Xbf + (size_t)(n0 + row) * NC + c0 + ck * 8);
      *(float4*)(&smem[row * 44 + ck * 8]) = av;
      float4 bv = *(const float4*)(HT + ((size_t)b * NM + m0 + row) * NC + c0 + ck * 8);
      *(float4*)(&smem[5632 + row * 44 + ck * 8]) = bv;
    }
    __syncthreads();
    bf16x8 a[4], bb[4];
#pragma unroll
    for (int f = 0; f < 4; ++f) {
      a[f] = *(const bf16x8*)(&smem[(wn + f * 16 + fr) * 44 + fq * 8]);
      bb[f] = *(const bf16x8*)(&smem[5632 + (wm + f * 16 + fr) * 44 + fq * 8]);
    }
#pragma unroll
    for (int i = 0; i < 4; ++i)
#pragma unroll
      for (int j = 0; j < 4; ++j)
        acc[i][j] = __builtin_amdgcn_mfma_f32_16x16x32_bf16(a[i], bb[j], acc[i][j], 0, 0, 0);
    __syncthreads();
  }
  float x2a[4][4];
#pragma unroll
  for (int fi = 0; fi < 4; ++fi) {
    float4 xv = *(const float4*)(x2 + n0 + wn + fi * 16 + fq * 4);
    x2a[fi][0] = xv.x; x2a[fi][1] = xv.y; x2a[fi][2] = xv.z; x2a[fi][3] = xv.w;
  }
  float y2a[4];
#pragma unroll
  for (int fj = 0; fj < 4; ++fj) y2a[fj] = y2[b * NM + m0 + wm + fj * 16 + fr];
  unsigned short kb[4][4][4];
#pragma unroll
  for (int fi = 0; fi < 4; ++fi)
#pragma unroll
    for (int fj = 0; fj < 4; ++fj)
#pragma unroll
      for (int r = 0; r < 4; ++r) {
        float cost = fmaxf(x2a[fi][r] + y2a[fj] - 2.0f * acc[fi][fj][r], 0.0f);
        kb[fi][fj][r] = f2bf(__expf(-cost * REG_INV));
      }
  // KT: two m-chunks (64 rows x 128 n), swizzled stage -> coalesced stores
#pragma unroll
  for (int h = 0; h < 2; ++h) {
    __syncthreads();
    if ((w & 1) == h) {
#pragma unroll
      for (int fj = 0; fj < 4; ++fj) {
        int rr = fj * 16 + fr;
#pragma unroll
        for (int fi = 0; fi < 4; ++fi) {
          int cc = wn + fi * 16 + fq * 4;
          ushort4 kt4 = {kb[fi][fj][0], kb[fi][fj][1], kb[fi][fj][2], kb[fi][fj][3]};
          *(ushort4*)&smem[rr * 136 + (cc ^ ((rr & 7) << 3))] = kt4;
        }
      }
    }
    __syncthreads();
#pragma unroll
    for (int p = 0; p < 4; ++p) {
      int row = p * 16 + (t >> 4), co = (t & 15) * 8;
      *(float4*)(KT + ((size_t)b * NM + m0 + h * 64 + row) * NN + n0 + co) =
          *(const float4*)&smem[row * 136 + (co ^ ((row & 7) << 3))];
    }
  }
}

// Per-KT-row (column of K) max + e5m2 quantization into separate fp8 buffer.
// K~T[m][n] = KT[m][n] * c[m], c = 32768/colmax. (scale cancels downstream)
__global__ __launch_bounds__(256) void requant_kernel(
    const unsigned short* __restrict__ KT, unsigned char* __restrict__ K8T) {
  const int row = blockIdx.x;  // 0..9215 (= b*NM + m)
  const int t = threadIdx.x, l = t & 63, wv = t >> 6;
  const unsigned short* src = KT + (size_t)row * NN + t * 16;
  float4 a0 = *(const float4*)(src);
  float4 a1 = *(const float4*)(src + 8);
  const unsigned short* s0 = (const unsigned short*)&a0;
  const unsigned short* s1 = (const unsigned short*)&a1;
  float mx = 0.f;
#pragma unroll
  for (int j = 0; j < 8; ++j)
    mx = fmaxf(mx, fmaxf(bf2f(s0[j]), bf2f(s1[j])));
#pragma unroll
  for (int off = 32; off > 0; off >>= 1) mx = fmaxf(mx, __shfl_xor(mx, off));
  __shared__ float wmx[4];
  if (l == 0) wmx[wv] = mx;
  __syncthreads();
  mx = fmaxf(fmaxf(wmx[0], wmx[1]), fmaxf(wmx[2], wmx[3]));
  float c = fminf(32768.0f / mx, 1e38f);
  unsigned int o[4] = {0, 0, 0, 0};
#pragma unroll
  for (int j = 0; j < 8; ++j) {
    o[j >> 2] |= (unsigned int)f2e5(bf2f(s0[j]) * c) << ((j & 3) * 8);
    o[2 + (j >> 2)] |= (unsigned int)f2e5(bf2f(s1[j]) * c) << ((j & 3) * 8);
  }
  uint4 ov = {o[0], o[1], o[2], o[3]};
  *(uint4*)(K8T + (size_t)row * NN + t * 16) = ov;
}

// Kernel A: finalize u (from usumR, omega via r*sqrt(r)), then direct v~ row
// dots over K~T with uint4 (16B/lane) loads. grid (192, 4): 12 m-rows/block.
__global__ __launch_bounds__(256) void vrow_kernel(
    const unsigned char* __restrict__ K8T, const float* __restrict__ usumR,
    float* __restrict__ usumZ, const float* __restrict__ uR,
    float* __restrict__ uW, float* __restrict__ uF, float* __restrict__ vB,
    const int* __restrict__ ncG, int* __restrict__ ncS, int force) {
  const int b = blockIdx.y, bx = blockIdx.x;
  const int t = threadIdx.x, l = t & 63, wv = t >> 6;
  if (bx == 0 && t == 0) ncS[b] = 0;  // pre-gate zero (sticky-done)
  if (ncG[b] == 0) return;
  __shared__ __align__(16) float uS[NN];
  int flag = force;
#pragma unroll
  for (int jj = 0; jj < 16; ++jj) {
    int i = jj * 256 + t;
    float us = usumR[b * NN + i];
    float uo = uR[b * NN + i];
    float ut = A_VAL / us;
    float r = ut / uo;
    float un = uo * r * sqrtf(r);  // r^1.5, no exp/log
    uS[i] = un;
    if (bx == 0) {
      uW[b * NN + i] = un;
      uF[b * NN + i] = un;
      if (fabsf(ut - uo) > EPS_CONV * uo) flag = 1;
    }
    if (bx == 1) usumZ[b * NN + i] = 0.f;
  }
  __syncthreads();
  if (bx == 0 && flag) ncS[b] = 1;  // ordered after t0's zero by the barrier
  const unsigned char* KTb = K8T + (size_t)(b * NM + bx * 12) * NN;
#pragma unroll 1
  for (int rr = 0; rr < 3; ++rr) {
    int row = wv * 3 + rr;  // 0..11
    const uint4* Kp4 = (const uint4*)(KTb + (size_t)row * NN);
    float s = 0.f;
#pragma unroll
    for (int p = 0; p < 4; ++p) {
      int idx = l + 64 * p;
      uint4 q4 = Kp4[idx];
      const float4* uu = ((const float4*)uS) + 4 * idx;
      float4 d;
      dec4(q4.x, d);
      s += d.x * uu[0].x + d.y * uu[0].y + d.z * uu[0].z + d.w * uu[0].w;
      dec4(q4.y, d);
      s += d.x * uu[1].x + d.y * uu[1].y + d.z * uu[1].z + d.w * uu[1].w;
      dec4(q4.z, d);
      s += d.x * uu[2].x + d.y * uu[2].y + d.z * uu[2].z + d.w * uu[2].w;
      dec4(q4.w, d);
      s += d.x * uu[3].x + d.y * uu[3].y + d.z * uu[3].z + d.w * uu[3].w;
    }
    s = waveSum(s);
    if (l == 0) vB[b * NM + bx * 12 + row] = B_VAL / s;
  }
}

// Kernel B: column partials with uint4 (16B/lane) loads.
// grid (4 nch x 1024n, 32 mch x 72m, 4) = 512 blocks. Wave wv handles
// m = 4i+wv (18 iters); lane owns 16 consecutive n. LDS cross-wave reduce,
// 4 atomics/thread (524K total/iter).
__global__ __launch_bounds__(256) void ucol_kernel(
    const unsigned char* __restrict__ K8T, const float* __restrict__ vB,
    float* __restrict__ usumA, const int* __restrict__ ncG) {
  const int b = blockIdx.z;
  if (ncG[b] == 0) return;
  const int nch = blockIdx.x;  // 0..3 (1024 n)
  const int mch = blockIdx.y;  // 0..31 (72 m)
  const int t = threadIdx.x, l = t & 63, wv = t >> 6;
  __shared__ float vS[72];
  __shared__ __align__(16) float red[4][1024];
  if (t < 72) vS[t] = vB[b * NM + mch * 72 + t];
  __syncthreads();
  const unsigned char* Kp =
      K8T + (size_t)(b * NM + mch * 72) * NN + nch * 1024 + l * 16;
  float4 p0 = {0.f, 0.f, 0.f, 0.f}, p1 = p0, p2 = p0, p3 = p0;
#pragma unroll 3
  for (int i = 0; i < 18; ++i) {
    int m = i * 4 + wv;
    uint4 q4 = *(const uint4*)(Kp + (size_t)m * NN);
    float vv = vS[m];
    float4 d;
    dec4(q4.x, d);
    p0.x += d.x * vv; p0.y += d.y * vv; p0.z += d.z * vv; p0.w += d.w * vv;
    dec4(q4.y, d);
    p1.x += d.x * vv; p1.y += d.y * vv; p1.z += d.z * vv; p1.w += d.w * vv;
    dec4(q4.z, d);
    p2.x += d.x * vv; p2.y += d.y * vv; p2.z += d.z * vv; p2.w += d.w * vv;
    dec4(q4.w, d);
    p3.x += d.x * vv; p3.y += d.y * vv; p3.z += d.z * vv; p3.w += d.w * vv;
  }
  *(float4*)&red[wv][l * 16 + 0] = p0;
  *(float4*)&red[wv][l * 16 + 4] = p1;
  *(float4*)&red[wv][l * 16 + 8] = p2;
  *(float4*)&red[wv][l * 16 + 12] = p3;
  __syncthreads();
  float4 s0 = *(const float4*)&red[0][t * 4];
  float4 s1 = *(const float4*)&red[1][t * 4];
  float4 s2 = *(const float4*)&red[2][t * 4];
  float4 s3 = *(const float4*)&red[3][t * 4];
  float* dst = usumA + (size_t)b * NN + nch * 1024 + t * 4;
  atomicAdd(dst + 0, s0.x + s1.x + s2.x + s3.x);
  atomicAdd(dst + 1, s0.y + s1.y + s2.y + s3.y);
  atomicAdd(dst + 2, s0.z + s1.z + s2.z + s3.z);
  atomicAdd(dst + 3, s0.w + s1.w + s2.w + s3.w);
}

// XT partial [kh] = v~[m] * sum_{n in half kh} XuT[c][n]*K~T[m][n].
// Split-K=2: grid (4, 36, 8), z = kh*4 + b. Tile 64c x 64m, BK=64.
__global__ __launch_bounds__(256) void xspace_mfma(
    const unsigned short* __restrict__ XuT, const unsigned char* __restrict__ K8T,
    const float* __restrict__ vB, float* __restrict__ XT0,
    float* __restrict__ XT1) {
  __shared__ unsigned short As[64][76];
  __shared__ unsigned short Bs[64][76];
  const int b = blockIdx.z & 3, kh = blockIdx.z >> 2;
  const int c0 = blockIdx.x * 64, m0 = blockIdx.y * 64;
  const int t = threadIdx.x, l = t & 63, w = t >> 6;
  const int wc = (w >> 1) * 32, wm = (w & 1) * 32;
  const int fr = l & 15, fq = l >> 4;
  f32x4 zero = {0.f, 0.f, 0.f, 0.f};
  f32x4 acc[2][2];
#pragma unroll
  for (int i = 0; i < 2; ++i)
#pragma unroll
    for (int j = 0; j < 2; ++j) acc[i][j] = zero;

  const int brow = t >> 2, bseg = t & 3;  // 64 rows x 4 segs x 16 fp8 bytes
  const int kbeg = kh * 2048;
  for (int k0 = kbeg; k0 < kbeg + 2048; k0 += 64) {
#pragma unroll
    for (int i = 0; i < 2; ++i) {
      int idx = t + i * 256;
      int row = idx >> 3, ck = idx & 7;
      *(float4*)(&As[row][ck * 8]) =
          *(const float4*)(XuT + ((size_t)b * NC + c0 + row) * NN + k0 + ck * 8);
    }
    {
      uint4 q4 = *(const uint4*)(K8T + ((size_t)b * NM + m0 + brow) * NN + k0 +
                                 bseg * 16);
      unsigned int ow[8];
      float4 d;
      dec4(q4.x, d);
      ow[0] = (__float_as_uint(d.x) >> 16) | (__float_as_uint(d.y) & 0xFFFF0000u);
      ow[1] = (__float_as_uint(d.z) >> 16) | (__float_as_uint(d.w) & 0xFFFF0000u);
      dec4(q4.y, d);
      ow[2] = (__float_as_uint(d.x) >> 16) | (__float_as_uint(d.y) & 0xFFFF0000u);
      ow[3] = (__float_as_uint(d.z) >> 16) | (__float_as_uint(d.w) & 0xFFFF0000u);
      dec4(q4.z, d);
      ow[4] = (__float_as_uint(d.x) >> 16) | (__float_as_uint(d.y) & 0xFFFF0000u);
      ow[5] = (__float_as_uint(d.z) >> 16) | (__float_as_uint(d.w) & 0xFFFF0000u);
      dec4(q4.w, d);
      ow[6] = (__float_as_uint(d.x) >> 16) | (__float_as_uint(d.y) & 0xFFFF0000u);
      ow[7] = (__float_as_uint(d.z) >> 16) | (__float_as_uint(d.w) & 0xFFFF0000u);
      uint2* bp = (uint2*)&Bs[brow][bseg * 16];
      bp[0] = make_uint2(ow[0], ow[1]);
      bp[1] = make_uint2(ow[2], ow[3]);
      bp[2] = make_uint2(ow[4], ow[5]);
      bp[3] = make_uint2(ow[6], ow[7]);
    }
    __syncthreads();
    bf16x8 a[2][2], bb[2][2];
#pragma unroll
    for (int f = 0; f < 2; ++f)
#pragma unroll
      for (int ks = 0; ks < 2; ++ks) {
        a[f][ks] = *(const bf16x8*)(&As[wc + f * 16 + fr][ks * 32 + fq * 8]);
        bb[f][ks] = *(const bf16x8*)(&Bs[wm + f * 16 + fr][ks * 32 + fq * 8]);
      }
#pragma unroll
    for (int ks = 0; ks < 2; ++ks)
#pragma unroll
      for (int i = 0; i < 2; ++i)
#pragma unroll
        for (int j = 0; j < 2; ++j)
          acc[i][j] = __builtin_amdgcn_mfma_f32_16x16x32_bf16(a[i][ks], bb[j][ks], acc[i][j], 0, 0, 0);
    __syncthreads();
  }
  float* XTo = kh ? XT1 : XT0;
#pragma unroll
  for (int fj = 0; fj < 2; ++fj) {
    int m = m0 + wm + fj * 16 + fr;
    float vm = vB[(size_t)b * NM + m];
#pragma unroll
    for (int fi = 0; fi < 2; ++fi) {
      int cb = c0 + wc + fi * 16 + fq * 4;
#pragma unroll
      for (int r = 0; r < 4; ++r)
        XTo[((size_t)b * NC + cb + r) * NM + m] = vm * acc[fi][fj][r];
    }
  }
}

// out_aligned = H + alpha*(XT0+XT1); out_feat = XT0+XT1; partial (H-XT)^2 sums
__global__ __launch_bounds__(256) void finalize_kernel(
    const float* __restrict__ H, const float* __restrict__ XT0,
    const float* __restrict__ XT1, float* __restrict__ out_aligned,
    float* __restrict__ out_feat, float* __restrict__ partials) {
  const int t = threadIdx.x;
  float s = 0.f;
  for (int i = blockIdx.x * 256 + t; i < OUT_ELEMS / 4; i += 1024 * 256) {
    float4 h = *(const float4*)(H + (size_t)i * 4);
    float4 xa = *(const float4*)(XT0 + (size_t)i * 4);
    float4 xb = *(const float4*)(XT1 + (size_t)i * 4);
    float4 x;
    x.x = xa.x + xb.x;
    x.y = xa.y + xb.y;
    x.z = xa.z + xb.z;
    x.w = xa.w + xb.w;
    float4 o;
    o.x = h.x + ALPHA_C * x.x;
    o.y = h.y + ALPHA_C * x.y;
    o.z = h.z + ALPHA_C * x.z;
    o.w = h.w + ALPHA_C * x.w;
    *(float4*)(out_aligned + (size_t)i * 4) = o;
    out_feat[(size_t)i * 4 + 0] = x.x;  // dest misaligned by 1 float -> scalar
    out_feat[(size_t)i * 4 + 1] = x.y;
    out_feat[(size_t)i * 4 + 2] = x.z;
    out_feat[(size_t)i * 4 + 3] = x.w;
    float dx = h.x - x.x, dy = h.y - x.y, dz = h.z - x.z, dw = h.w - x.w;
    s += dx * dx + dy * dy + dz * dz + dw * dw;
  }
  s = waveSum(s);
  __shared__ float ws_[4];
  if ((t & 63) == 0) ws_[t >> 6] = s;
  __syncthreads();
  if (t == 0) partials[blockIdx.x] = ws_[0] + ws_[1] + ws_[2] + ws_[3];
}

__global__ __launch_bounds__(256) void lot_kernel(
    const float* __restrict__ partials, float* __restrict__ out_lot) {
  float s = 0.f;
  for (int i = threadIdx.x; i < 1024; i += 256) s += partials[i];
  s = waveSum(s);
  __shared__ float ws_[4];
  if ((threadIdx.x & 63) == 0) ws_[threadIdx.x >> 6] = s;
  __syncthreads();
  if (threadIdx.x == 0)
    out_lot[0] = (ws_[0] + ws_[1] + ws_[2] + ws_[3]) / (float)OUT_ELEMS;
}

extern "C" void kernel_launch(void* const* d_in, const int* in_sizes, int n_in,
                              void* d_out, int out_size, void* d_ws,
                              size_t ws_size, hipStream_t stream) {
  const float* X = (const float*)d_in[0];  // sc (4096,256)
  const float* H = (const float*)d_in[1];  // h_spot (4,256,48,48)
  float* out = (float*)d_out;
  char* ws = (char*)d_ws;

  // workspace layout (bytes)
  unsigned short* KT = (unsigned short*)(ws);           // 75,497,472 (bf16, requant input)
  unsigned char* K8T = (unsigned char*)(ws + 75497472); // 37,748,736 (fp8: loop + xspace)
  float* XT0 = (float*)(ws + 113246208);                // 9,437,184
  // aliases inside XT0 region (dead before xspace writes):
  unsigned short* Xbf = (unsigned short*)(ws + 113246208);           // 2,097,152
  unsigned short* HT = (unsigned short*)(ws + 113246208 + 2097152);  // 4,718,592
  float* usum = (float*)(ws + 122683392);   // 2 slots x 65,536
  float* u = (float*)(ws + 122814464);      // 2 slots x 65,536
  float* uF = (float*)(ws + 122945536);     // 65,536
  float* vB = (float*)(ws + 123011072);     // 36,864
  float* x2 = (float*)(ws + 123047936);     // 16,384
  float* y2 = (float*)(ws + 123064320);     // 36,864
  int* nc = (int*)(ws + 123101184);         // 32
  float* partials = (float*)(ws + 123101216);  // 4,096
  unsigned short* XuT = (unsigned short*)(ws + 125829120);  // 8,388,608
  float* XT1 = (float*)(ws + 134217728);    // 9,437,184 -> ends 143,654,912
  if (ws_size < (size_t)143654912) return;

  x2_kernel<<<1024, 256, 0, stream>>>(X, x2);
  y2_kernel<<<36, 256, 0, stream>>>(H, y2);
  prep_xbf<<<1024, 256, 0, stream>>>(X, Xbf);
  prep_ht<<<dim3(72, 8, 4), 256, 0, stream>>>(H, HT);
  cost_k_mfma<<<dim3(32, 18, 4), 256, 0, stream>>>(Xbf, HT, x2, y2, KT);
  requant_kernel<<<9216, 256, 0, stream>>>(KT, K8T);
  init_kernel<<<64, 256, 0, stream>>>(usum, u, nc);
  for (int it = 0; it < MAX_IT; ++it) {
    const int p = it & 1, q = 1 - p;
    // A: gate nc[q], set nc[p]; read usum[p], zero usum[q]; read u[p], write u[q]
    vrow_kernel<<<dim3(192, 4), 256, 0, stream>>>(
        K8T, usum + (size_t)p * 4 * NN, usum + (size_t)q * 4 * NN,
        u + (size_t)p * 4 * NN, u + (size_t)q * 4 * NN, uF, vB,
        nc + q * 4, nc + p * 4, it == 0 ? 1 : 0);
    // B: gate nc[q]; accumulate usum[q]
    ucol_kernel<<<dim3(4, 32, 4), 256, 0, stream>>>(
        K8T, vB, usum + (size_t)q * 4 * NN, nc + q * 4);
  }
  prep_xut<<<dim3(128, 8, 4), 256, 0, stream>>>(X, uF, XuT);
  xspace_mfma<<<dim3(4, 36, 8), 256, 0, stream>>>(XuT, K8T, vB, XT0, XT1);
  finalize_kernel<<<1024, 256, 0, stream>>>(H, XT0, XT1, out,
                                            out + OUT_ELEMS + 1, partials);
  lot_kernel<<<1, 256, 0, stream>>>(partials, out + OUT_ELEMS);
}

// Round 13
// 566.741 us; speedup vs baseline: 1.3418x; 1.3418x over previous
//
#include <hip/hip_runtime.h>
#include <hip/hip_fp16.h>

#define NN 4096
#define NM 2304
#define NC 256
#define OUT_ELEMS 2359296  // 4*256*48*48
#define MAX_IT 18

static constexpr float REG_INV = 0.1f;      // 1/REG
static constexpr float A_VAL = 1.0f / 4096.0f;
static constexpr float B_VAL = 1.0f / 2304.0f;
static constexpr float ALPHA_C = 0.001f;
static constexpr float EPS_CONV = 1e-5f;  // r9-proven
// over-relaxation u' = u*(ut/u)^1.25 via r*sqrt(sqrt(r)); omega=1.25 ~ SOR-optimal
// (rho~0.7 measured r2/r3 -> omega*=1.17, complex regime rate = omega-1 = 0.25)

typedef __attribute__((ext_vector_type(8))) short bf16x8;
typedef __attribute__((ext_vector_type(4))) float f32x4;
typedef __attribute__((ext_vector_type(2))) float f32x2;

__device__ __forceinline__ float bf2f(unsigned short h) {
  return __uint_as_float(((unsigned int)h) << 16);
}
__device__ __forceinline__ unsigned short f2bf(float f) {
  unsigned int u = __float_as_uint(f);
  unsigned int r = (u + 0x7FFFu + ((u >> 16) & 1u)) >> 16;  // RNE
  return (unsigned short)r;
}
// e5m2 encode: f32 -> f16 (RNE) -> top byte with RNE on bit 7
__device__ __forceinline__ unsigned char f2e5(float x) {
  unsigned short h = __half_as_ushort(__float2half_rn(x));
  return (unsigned char)((h + 0x7Fu + ((h >> 8) & 1u)) >> 8);
}
__device__ __forceinline__ float e52f(unsigned int hs) {
  return __half2float(__ushort_as_half((unsigned short)hs));
}
// decode 4 packed e5m2 (bf8) bytes -> 4 floats
__device__ __forceinline__ void dec4(unsigned int q, float4& o) {
#if __has_builtin(__builtin_amdgcn_cvt_pk_f32_bf8)
  f32x2 lo = __builtin_amdgcn_cvt_pk_f32_bf8((int)q, false);
  f32x2 hi = __builtin_amdgcn_cvt_pk_f32_bf8((int)q, true);
  o.x = lo[0]; o.y = lo[1]; o.z = hi[0]; o.w = hi[1];
#else
  o.x = e52f((q << 8) & 0xFF00u);
  o.y = e52f(q & 0xFF00u);
  o.z = e52f((q >> 8) & 0xFF00u);
  o.w = e52f((q >> 16) & 0xFF00u);
#endif
}
__device__ __forceinline__ float waveSum(float s) {
#pragma unroll
  for (int off = 32; off > 0; off >>= 1) s += __shfl_xor(s, off);
  return s;
}

// x2[n] = sum_c X[n][c]^2 ; one wave per row
__global__ __launch_bounds__(256) void x2_kernel(const float* __restrict__ X,
                                                 float* __restrict__ x2) {
  int wid = threadIdx.x >> 6, lane = threadIdx.x & 63;
  int row = blockIdx.x * 4 + wid;
  float4 v = *(const float4*)(X + (size_t)row * NC + lane * 4);
  float s = v.x * v.x + v.y * v.y + v.z * v.z + v.w * v.w;
  s = waveSum(s);
  if (lane == 0) x2[row] = s;
}

// y2[b][m] = sum_c H[b][c][m]^2 ; grid (72, 4): 32 m/block, 8 c-groups
__global__ __launch_bounds__(256) void y2_kernel(const float* __restrict__ H,
                                                 float* __restrict__ y2) {
  const int b = blockIdx.y;
  const int m0 = blockIdx.x * 32;
  const int t = threadIdx.x;
  const int ml = t & 31, cg = t >> 5;
  const float* p = H + ((size_t)b * NC + cg) * NM + m0 + ml;
  float s = 0.f;
#pragma unroll 8
  for (int i = 0; i < 32; ++i) {
    float v = p[(size_t)i * 8 * NM];
    s += v * v;
  }
  __shared__ float red[8][33];
  red[cg][ml] = s;
  __syncthreads();
  if (t < 32) {
    float tot = 0.f;
#pragma unroll
    for (int g = 0; g < 8; ++g) tot += red[g][t];
    y2[b * NM + m0 + t] = tot;
  }
}

// Xbf = bf16(X); grid 1024
__global__ __launch_bounds__(256) void prep_xbf(const float* __restrict__ X,
                                                unsigned short* __restrict__ Xbf) {
  size_t i = blockIdx.x * 256 + threadIdx.x;
  float4 xv = *(const float4*)(X + i * 4);
  ushort4 o = {f2bf(xv.x), f2bf(xv.y), f2bf(xv.z), f2bf(xv.w)};
  *(ushort4*)(Xbf + i * 4) = o;
}

// HT[b][m][c] = bf16(H[b][c][m]); grid (72, 8, 4)
__global__ __launch_bounds__(256) void prep_ht(const float* __restrict__ H,
                                               unsigned short* __restrict__ HT) {
  __shared__ unsigned short tile[32][34];
  const int b = blockIdx.z;
  const int mt = blockIdx.x * 32, ct = blockIdx.y * 32;
  const int t = threadIdx.x;
#pragma unroll
  for (int p = 0; p < 4; ++p) {
    int c = ct + p * 8 + (t >> 5);
    tile[t & 31][p * 8 + (t >> 5)] = f2bf(H[((size_t)b * NC + c) * NM + mt + (t & 31)]);
  }
  __syncthreads();
#pragma unroll
  for (int p = 0; p < 4; ++p) {
    int mloc = p * 8 + (t >> 5);
    HT[((size_t)b * NM + mt + mloc) * NC + ct + (t & 31)] = tile[mloc][t & 31];
  }
}

// XuT[b][c][n] = bf16(u[n]*X[n][c]); grid (128, 8, 4)
__global__ __launch_bounds__(256) void prep_xut(const float* __restrict__ X,
                                                const float* __restrict__ uF,
                                                unsigned short* __restrict__ XuT) {
  __shared__ unsigned short tile[32][34];
  const int b = blockIdx.z;
  const int nt = blockIdx.x * 32, ct = blockIdx.y * 32;
  const int t = threadIdx.x;
#pragma unroll
  for (int p = 0; p < 4; ++p) {
    int nloc = p * 8 + (t >> 5);
    float uu = uF[b * NN + nt + nloc];
    tile[nloc][t & 31] = f2bf(uu * X[(size_t)(nt + nloc) * NC + ct + (t & 31)]);
  }
  __syncthreads();
#pragma unroll
  for (int p = 0; p < 4; ++p) {
    int cloc = p * 8 + (t >> 5);
    XuT[((size_t)b * NC + ct + cloc) * NN + nt + (t & 31)] = tile[t & 31][cloc];
  }
}

// usum slot0 = 1.0 (seed: u0 = A/1 -> identity), u slot0 = A_VAL, nc = 1
__global__ __launch_bounds__(256) void init_kernel(float* __restrict__ usum0,
                                                   float* __restrict__ u0,
                                                   int* __restrict__ nc) {
  int gid = blockIdx.x * 256 + threadIdx.x;  // grid 64 -> 16384
  usum0[gid] = 1.0f;
  u0[gid] = A_VAL;
  if (gid < 8) nc[gid] = 1;
}

// MFMA cost kernel: tile 128n x 128m, 4 waves (2x2), c-steps of 32.
// Writes ONLY KT[b][m][n] (bf16) via LDS-staged coalesced float4 stores.
__global__ __launch_bounds__(256) void cost_k_mfma(
    const unsigned short* __restrict__ Xbf, const unsigned short* __restrict__ HT,
    const float* __restrict__ x2, const float* __restrict__ y2,
    unsigned short* __restrict__ KT) {
  __shared__ __align__(16) unsigned short smem[128 * 88];
  const int b = blockIdx.z;
  const int n0 = blockIdx.x * 128, m0 = blockIdx.y * 128;
  const int t = threadIdx.x, l = t & 63, w = t >> 6;
  const int wn = (w >> 1) * 64, wm = (w & 1) * 64;
  const int fr = l & 15, fq = l >> 4;
  f32x4 zero = {0.f, 0.f, 0.f, 0.f};
  f32x4 acc[4][4];
#pragma unroll
  for (int i = 0; i < 4; ++i)
#pragma unroll
    for (int j = 0; j < 4; ++j) acc[i][j] = zero;

  for (int c0 = 0; c0 < NC; c0 += 32) {
#pragma unroll
    for (int i = 0; i < 2; ++i) {
      int idx = t + i * 256;
      int row = idx >> 2, ck = idx & 3;
      float4 av = *(const float4*)(Xbf + (size_t)(n0 + row) * NC + c0 + ck * 8);
      *(float4*)(&smem[row * 44 + ck * 8]) = av;
      float4 bv = *(const float4*)(HT + ((size_t)b * NM + m0 + row) * NC + c0 + ck * 8);
      *(float4*)(&smem[5632 + row * 44 + ck * 8]) = bv;
    }
    __syncthreads();
    bf16x8 a[4], bb[4];
#pragma unroll
    for (int f = 0; f < 4; ++f) {
      a[f] = *(const bf16x8*)(&smem[(wn + f * 16 + fr) * 44 + fq * 8]);
      bb[f] = *(const bf16x8*)(&smem[5632 + (wm + f * 16 + fr) * 44 + fq * 8]);
    }
#pragma unroll
    for (int i = 0; i < 4; ++i)
#pragma unroll
      for (int j = 0; j < 4; ++j)
        acc[i][j] = __builtin_amdgcn_mfma_f32_16x16x32_bf16(a[i], bb[j], acc[i][j], 0, 0, 0);
    __syncthreads();
  }
  float x2a[4][4];
#pragma unroll
  for (int fi = 0; fi < 4; ++fi) {
    float4 xv = *(const float4*)(x2 + n0 + wn + fi * 16 + fq * 4);
    x2a[fi][0] = xv.x; x2a[fi][1] = xv.y; x2a[fi][2] = xv.z; x2a[fi][3] = xv.w;
  }
  float y2a[4];
#pragma unroll
  for (int fj = 0; fj < 4; ++fj) y2a[fj] = y2[b * NM + m0 + wm + fj * 16 + fr];
  unsigned short kb[4][4][4];
#pragma unroll
  for (int fi = 0; fi < 4; ++fi)
#pragma unroll
    for (int fj = 0; fj < 4; ++fj)
#pragma unroll
      for (int r = 0; r < 4; ++r) {
        float cost = fmaxf(x2a[fi][r] + y2a[fj] - 2.0f * acc[fi][fj][r], 0.0f);
        kb[fi][fj][r] = f2bf(__expf(-cost * REG_INV));
      }
  // KT: two m-chunks (64 rows x 128 n), swizzled stage -> coalesced stores
#pragma unroll
  for (int h = 0; h < 2; ++h) {
    __syncthreads();
    if ((w & 1) == h) {
#pragma unroll
      for (int fj = 0; fj < 4; ++fj) {
        int rr = fj * 16 + fr;
#pragma unroll
        for (int fi = 0; fi < 4; ++fi) {
          int cc = wn + fi * 16 + fq * 4;
          ushort4 kt4 = {kb[fi][fj][0], kb[fi][fj][1], kb[fi][fj][2], kb[fi][fj][3]};
          *(ushort4*)&smem[rr * 136 + (cc ^ ((rr & 7) << 3))] = kt4;
        }
      }
    }
    __syncthreads();
#pragma unroll
    for (int p = 0; p < 4; ++p) {
      int row = p * 16 + (t >> 4), co = (t & 15) * 8;
      *(float4*)(KT + ((size_t)b * NM + m0 + h * 64 + row) * NN + n0 + co) =
          *(const float4*)&smem[row * 136 + (co ^ ((row & 7) << 3))];
    }
  }
}

// Per-KT-row (column of K) max + e5m2 quantization into separate fp8 buffer.
// K~T[m][n] = KT[m][n] * c[m], c = 32768/colmax. (scale cancels downstream)
__global__ __launch_bounds__(256) void requant_kernel(
    const unsigned short* __restrict__ KT, unsigned char* __restrict__ K8T) {
  const int row = blockIdx.x;  // 0..9215 (= b*NM + m)
  const int t = threadIdx.x, l = t & 63, wv = t >> 6;
  const unsigned short* src = KT + (size_t)row * NN + t * 16;
  float4 a0 = *(const float4*)(src);
  float4 a1 = *(const float4*)(src + 8);
  const unsigned short* s0 = (const unsigned short*)&a0;
  const unsigned short* s1 = (const unsigned short*)&a1;
  float mx = 0.f;
#pragma unroll
  for (int j = 0; j < 8; ++j)
    mx = fmaxf(mx, fmaxf(bf2f(s0[j]), bf2f(s1[j])));
#pragma unroll
  for (int off = 32; off > 0; off >>= 1) mx = fmaxf(mx, __shfl_xor(mx, off));
  __shared__ float wmx[4];
  if (l == 0) wmx[wv] = mx;
  __syncthreads();
  mx = fmaxf(fmaxf(wmx[0], wmx[1]), fmaxf(wmx[2], wmx[3]));
  float c = fminf(32768.0f / mx, 1e38f);
  unsigned int o[4] = {0, 0, 0, 0};
#pragma unroll
  for (int j = 0; j < 8; ++j) {
    o[j >> 2] |= (unsigned int)f2e5(bf2f(s0[j]) * c) << ((j & 3) * 8);
    o[2 + (j >> 2)] |= (unsigned int)f2e5(bf2f(s1[j]) * c) << ((j & 3) * 8);
  }
  uint4 ov = {o[0], o[1], o[2], o[3]};
  *(uint4*)(K8T + (size_t)row * NN + t * 16) = ov;
}

// Kernel A (r11-proven): finalize u (omega=1.25 via r*sqrt(sqrt(r))), then v~
// row dots over K~T with 4B loads (conflict-free LDS). grid (192, 4).
__global__ __launch_bounds__(256) void vrow_kernel(
    const unsigned char* __restrict__ K8T, const float* __restrict__ usumR,
    float* __restrict__ usumZ, const float* __restrict__ uR,
    float* __restrict__ uW, float* __restrict__ uF, float* __restrict__ vB,
    const int* __restrict__ ncG, int* __restrict__ ncS, int force) {
  const int b = blockIdx.y, bx = blockIdx.x;
  const int t = threadIdx.x, l = t & 63, wv = t >> 6;
  if (bx == 0 && t == 0) ncS[b] = 0;  // pre-gate zero (sticky-done)
  if (ncG[b] == 0) return;
  __shared__ __align__(16) float uS[NN];
  int flag = force;
#pragma unroll
  for (int jj = 0; jj < 16; ++jj) {
    int i = jj * 256 + t;
    float us = usumR[b * NN + i];
    float uo = uR[b * NN + i];
    float ut = A_VAL / us;
    float r = ut / uo;
    float un = uo * r * sqrtf(sqrtf(r));  // r^1.25
    uS[i] = un;
    if (bx == 0) {
      uW[b * NN + i] = un;
      uF[b * NN + i] = un;
      if (fabsf(ut - uo) > EPS_CONV * uo) flag = 1;
    }
    if (bx == 1) usumZ[b * NN + i] = 0.f;
  }
  __syncthreads();
  if (bx == 0 && flag) ncS[b] = 1;  // ordered after t0's zero by the barrier
  const unsigned char* KTb = K8T + (size_t)(b * NM + bx * 12) * NN;
#pragma unroll 1
  for (int rr = 0; rr < 3; ++rr) {
    int row = wv * 3 + rr;  // 0..11
    const unsigned int* Kp = (const unsigned int*)(KTb + (size_t)row * NN);
    float s = 0.f;
#pragma unroll
    for (int p = 0; p < 16; ++p) {
      unsigned int q = Kp[l + 64 * p];
      float4 d;
      dec4(q, d);
      float4 uu = ((const float4*)uS)[l + 64 * p];
      s += d.x * uu.x + d.y * uu.y + d.z * uu.z + d.w * uu.w;
    }
    s = waveSum(s);
    if (l == 0) vB[b * NM + bx * 12 + row] = B_VAL / s;
  }
}

// Kernel B (r11-proven): tiled column partials: usumA[n] += sum_m K~T[m][n]*v~[m].
// grid (16 nch, 8 mch, 4): 288 m x 256 n tiles; LDS cross-wave reduce ->
// 256 atomics/block (131K total).
__global__ __launch_bounds__(256) void ucol_kernel(
    const unsigned char* __restrict__ K8T, const float* __restrict__ vB,
    float* __restrict__ usumA, const int* __restrict__ ncG) {
  const int b = blockIdx.z;
  if (ncG[b] == 0) return;
  const int nch = blockIdx.x;  // 0..15 (256 n)
  const int mch = blockIdx.y;  // 0..7  (288 m)
  const int t = threadIdx.x, l = t & 63, wv = t >> 6;
  __shared__ float vS[288];
  __shared__ __align__(16) float red[4][64][4];
  for (int i = t; i < 288; i += 256) vS[i] = vB[b * NM + mch * 288 + i];
  __syncthreads();
  const unsigned char* Kp =
      K8T + (size_t)(b * NM + mch * 288) * NN + nch * 256 + l * 4;
  float4 acc = {0.f, 0.f, 0.f, 0.f};
#pragma unroll 8
  for (int i = 0; i < 72; ++i) {
    int m = i * 4 + wv;
    unsigned int q = *(const unsigned int*)(Kp + (size_t)m * NN);
    float4 d;
    dec4(q, d);
    float vv = vS[m];
    acc.x += d.x * vv;
    acc.y += d.y * vv;
    acc.z += d.z * vv;
    acc.w += d.w * vv;
  }
  *(float4*)red[wv][l] = acc;
  __syncthreads();
  if (wv == 0) {
    float4 a0 = *(float4*)red[0][l];
    float4 a1 = *(float4*)red[1][l];
    float4 a2 = *(float4*)red[2][l];
    float4 a3 = *(float4*)red[3][l];
    float* dst = usumA + (size_t)b * NN + nch * 256 + l * 4;
    atomicAdd(dst + 0, a0.x + a1.x + a2.x + a3.x);
    atomicAdd(dst + 1, a0.y + a1.y + a2.y + a3.y);
    atomicAdd(dst + 2, a0.z + a1.z + a2.z + a3.z);
    atomicAdd(dst + 3, a0.w + a1.w + a2.w + a3.w);
  }
}

// XT partial [kh] = v~[m] * sum_{n in half kh} XuT[c][n]*K~T[m][n].
// Split-K=2 (r12-proven): grid (4, 36, 8), z = kh*4 + b. Tile 64c x 64m, BK=64.
__global__ __launch_bounds__(256) void xspace_mfma(
    const unsigned short* __restrict__ XuT, const unsigned char* __restrict__ K8T,
    const float* __restrict__ vB, float* __restrict__ XT0,
    float* __restrict__ XT1) {
  __shared__ unsigned short As[64][76];
  __shared__ unsigned short Bs[64][76];
  const int b = blockIdx.z & 3, kh = blockIdx.z >> 2;
  const int c0 = blockIdx.x * 64, m0 = blockIdx.y * 64;
  const int t = threadIdx.x, l = t & 63, w = t >> 6;
  const int wc = (w >> 1) * 32, wm = (w & 1) * 32;
  const int fr = l & 15, fq = l >> 4;
  f32x4 zero = {0.f, 0.f, 0.f, 0.f};
  f32x4 acc[2][2];
#pragma unroll
  for (int i = 0; i < 2; ++i)
#pragma unroll
    for (int j = 0; j < 2; ++j) acc[i][j] = zero;

  const int brow = t >> 2, bseg = t & 3;  // 64 rows x 4 segs x 16 fp8 bytes
  const int kbeg = kh * 2048;
  for (int k0 = kbeg; k0 < kbeg + 2048; k0 += 64) {
#pragma unroll
    for (int i = 0; i < 2; ++i) {
      int idx = t + i * 256;
      int row = idx >> 3, ck = idx & 7;
      *(float4*)(&As[row][ck * 8]) =
          *(const float4*)(XuT + ((size_t)b * NC + c0 + row) * NN + k0 + ck * 8);
    }
    {
      uint4 q4 = *(const uint4*)(K8T + ((size_t)b * NM + m0 + brow) * NN + k0 +
                                 bseg * 16);
      unsigned int ow[8];
      float4 d;
      dec4(q4.x, d);
      ow[0] = (__float_as_uint(d.x) >> 16) | (__float_as_uint(d.y) & 0xFFFF0000u);
      ow[1] = (__float_as_uint(d.z) >> 16) | (__float_as_uint(d.w) & 0xFFFF0000u);
      dec4(q4.y, d);
      ow[2] = (__float_as_uint(d.x) >> 16) | (__float_as_uint(d.y) & 0xFFFF0000u);
      ow[3] = (__float_as_uint(d.z) >> 16) | (__float_as_uint(d.w) & 0xFFFF0000u);
      dec4(q4.z, d);
      ow[4] = (__float_as_uint(d.x) >> 16) | (__float_as_uint(d.y) & 0xFFFF0000u);
      ow[5] = (__float_as_uint(d.z) >> 16) | (__float_as_uint(d.w) & 0xFFFF0000u);
      dec4(q4.w, d);
      ow[6] = (__float_as_uint(d.x) >> 16) | (__float_as_uint(d.y) & 0xFFFF0000u);
      ow[7] = (__float_as_uint(d.z) >> 16) | (__float_as_uint(d.w) & 0xFFFF0000u);
      uint2* bp = (uint2*)&Bs[brow][bseg * 16];
      bp[0] = make_uint2(ow[0], ow[1]);
      bp[1] = make_uint2(ow[2], ow[3]);
      bp[2] = make_uint2(ow[4], ow[5]);
      bp[3] = make_uint2(ow[6], ow[7]);
    }
    __syncthreads();
    bf16x8 a[2][2], bb[2][2];
#pragma unroll
    for (int f = 0; f < 2; ++f)
#pragma unroll
      for (int ks = 0; ks < 2; ++ks) {
        a[f][ks] = *(const bf16x8*)(&As[wc + f * 16 + fr][ks * 32 + fq * 8]);
        bb[f][ks] = *(const bf16x8*)(&Bs[wm + f * 16 + fr][ks * 32 + fq * 8]);
      }
#pragma unroll
    for (int ks = 0; ks < 2; ++ks)
#pragma unroll
      for (int i = 0; i < 2; ++i)
#pragma unroll
        for (int j = 0; j < 2; ++j)
          acc[i][j] = __builtin_amdgcn_mfma_f32_16x16x32_bf16(a[i][ks], bb[j][ks], acc[i][j], 0, 0, 0);
    __syncthreads();
  }
  float* XTo = kh ? XT1 : XT0;
#pragma unroll
  for (int fj = 0; fj < 2; ++fj) {
    int m = m0 + wm + fj * 16 + fr;
    float vm = vB[(size_t)b * NM + m];
#pragma unroll
    for (int fi = 0; fi < 2; ++fi) {
      int cb = c0 + wc + fi * 16 + fq * 4;
#pragma unroll
      for (int r = 0; r < 4; ++r)
        XTo[((size_t)b * NC + cb + r) * NM + m] = vm * acc[fi][fj][r];
    }
  }
}

// out_aligned = H + alpha*(XT0+XT1); out_feat = XT0+XT1; partial (H-XT)^2 sums
__global__ __launch_bounds__(256) void finalize_kernel(
    const float* __restrict__ H, const float* __restrict__ XT0,
    const float* __restrict__ XT1, float* __restrict__ out_aligned,
    float* __restrict__ out_feat, float* __restrict__ partials) {
  const int t = threadIdx.x;
  float s = 0.f;
  for (int i = blockIdx.x * 256 + t; i < OUT_ELEMS / 4; i += 1024 * 256) {
    float4 h = *(const float4*)(H + (size_t)i * 4);
    float4 xa = *(const float4*)(XT0 + (size_t)i * 4);
    float4 xb = *(const float4*)(XT1 + (size_t)i * 4);
    float4 x;
    x.x = xa.x + xb.x;
    x.y = xa.y + xb.y;
    x.z = xa.z + xb.z;
    x.w = xa.w + xb.w;
    float4 o;
    o.x = h.x + ALPHA_C * x.x;
    o.y = h.y + ALPHA_C * x.y;
    o.z = h.z + ALPHA_C * x.z;
    o.w = h.w + ALPHA_C * x.w;
    *(float4*)(out_aligned + (size_t)i * 4) = o;
    out_feat[(size_t)i * 4 + 0] = x.x;  // dest misaligned by 1 float -> scalar
    out_feat[(size_t)i * 4 + 1] = x.y;
    out_feat[(size_t)i * 4 + 2] = x.z;
    out_feat[(size_t)i * 4 + 3] = x.w;
    float dx = h.x - x.x, dy = h.y - x.y, dz = h.z - x.z, dw = h.w - x.w;
    s += dx * dx + dy * dy + dz * dz + dw * dw;
  }
  s = waveSum(s);
  __shared__ float ws_[4];
  if ((t & 63) == 0) ws_[t >> 6] = s;
  __syncthreads();
  if (t == 0) partials[blockIdx.x] = ws_[0] + ws_[1] + ws_[2] + ws_[3];
}

__global__ __launch_bounds__(256) void lot_kernel(
    const float* __restrict__ partials, float* __restrict__ out_lot) {
  float s = 0.f;
  for (int i = threadIdx.x; i < 1024; i += 256) s += partials[i];
  s = waveSum(s);
  __shared__ float ws_[4];
  if ((threadIdx.x & 63) == 0) ws_[threadIdx.x >> 6] = s;
  __syncthreads();
  if (threadIdx.x == 0)
    out_lot[0] = (ws_[0] + ws_[1] + ws_[2] + ws_[3]) / (float)OUT_ELEMS;
}

extern "C" void kernel_launch(void* const* d_in, const int* in_sizes, int n_in,
                              void* d_out, int out_size, void* d_ws,
                              size_t ws_size, hipStream_t stream) {
  const float* X = (const float*)d_in[0];  // sc (4096,256)
  const float* H = (const float*)d_in[1];  // h_spot (4,256,48,48)
  float* out = (float*)d_out;
  char* ws = (char*)d_ws;

  // workspace layout (bytes)
  unsigned short* KT = (unsigned short*)(ws);           // 75,497,472 (bf16, requant input)
  unsigned char* K8T = (unsigned char*)(ws + 75497472); // 37,748,736 (fp8: loop + xspace)
  float* XT0 = (float*)(ws + 113246208);                // 9,437,184
  // aliases inside XT0 region (dead before xspace writes):
  unsigned short* Xbf = (unsigned short*)(ws + 113246208);           // 2,097,152
  unsigned short* HT = (unsigned short*)(ws + 113246208 + 2097152);  // 4,718,592
  float* usum = (float*)(ws + 122683392);   // 2 slots x 65,536
  float* u = (float*)(ws + 122814464);      // 2 slots x 65,536
  float* uF = (float*)(ws + 122945536);     // 65,536
  float* vB = (float*)(ws + 123011072);     // 36,864
  float* x2 = (float*)(ws + 123047936);     // 16,384
  float* y2 = (float*)(ws + 123064320);     // 36,864
  int* nc = (int*)(ws + 123101184);         // 32
  float* partials = (float*)(ws + 123101216);  // 4,096
  unsigned short* XuT = (unsigned short*)(ws + 125829120);  // 8,388,608
  float* XT1 = (float*)(ws + 134217728);    // 9,437,184 -> ends 143,654,912
  if (ws_size < (size_t)143654912) return;

  x2_kernel<<<1024, 256, 0, stream>>>(X, x2);
  y2_kernel<<<dim3(72, 4), 256, 0, stream>>>(H, y2);
  prep_xbf<<<1024, 256, 0, stream>>>(X, Xbf);
  prep_ht<<<dim3(72, 8, 4), 256, 0, stream>>>(H, HT);
  cost_k_mfma<<<dim3(32, 18, 4), 256, 0, stream>>>(Xbf, HT, x2, y2, KT);
  requant_kernel<<<9216, 256, 0, stream>>>(KT, K8T);
  init_kernel<<<64, 256, 0, stream>>>(usum, u, nc);
  for (int it = 0; it < MAX_IT; ++it) {
    const int p = it & 1, q = 1 - p;
    // A: gate nc[q], set nc[p]; read usum[p], zero usum[q]; read u[p], write u[q]
    vrow_kernel<<<dim3(192, 4), 256, 0, stream>>>(
        K8T, usum + (size_t)p * 4 * NN, usum + (size_t)q * 4 * NN,
        u + (size_t)p * 4 * NN, u + (size_t)q * 4 * NN, uF, vB,
        nc + q * 4, nc + p * 4, it == 0 ? 1 : 0);
    // B: gate nc[q]; accumulate usum[q]
    ucol_kernel<<<dim3(16, 8, 4), 256, 0, stream>>>(
        K8T, vB, usum + (size_t)q * 4 * NN, nc + q * 4);
  }
  prep_xut<<<dim3(128, 8, 4), 256, 0, stream>>>(X, uF, XuT);
  xspace_mfma<<<dim3(4, 36, 8), 256, 0, stream>>>(XuT, K8T, vB, XT0, XT1);
  finalize_kernel<<<1024, 256, 0, stream>>>(H, XT0, XT1, out,
                                            out + OUT_ELEMS + 1, partials);
  lot_kernel<<<1, 256, 0, stream>>>(partials, out + OUT_ELEMS);
}

// Round 14
// 488.831 us; speedup vs baseline: 1.5557x; 1.1594x over previous
//
#include <hip/hip_runtime.h>
#include <hip/hip_fp16.h>

#define NN 4096
#define NM 2304
#define NC 256
#define OUT_ELEMS 2359296  // 4*256*48*48
#define MAX_IT 14

static constexpr float REG_INV = 0.1f;      // 1/REG
static constexpr float A_VAL = 1.0f / 4096.0f;
static constexpr float B_VAL = 1.0f / 2304.0f;
static constexpr float ALPHA_C = 0.001f;
static constexpr float EPS_CONV = 1e-4f;  // residual 1e-4 << fp8 error 2e-3
// over-relaxation u' = u*(ut/u)^1.25 via r*sqrt(sqrt(r)); omega=1.25 ~ SOR-optimal

typedef __attribute__((ext_vector_type(8))) short bf16x8;
typedef __attribute__((ext_vector_type(4))) float f32x4;
typedef __attribute__((ext_vector_type(2))) float f32x2;

__device__ __forceinline__ float bf2f(unsigned short h) {
  return __uint_as_float(((unsigned int)h) << 16);
}
__device__ __forceinline__ unsigned short f2bf(float f) {
  unsigned int u = __float_as_uint(f);
  unsigned int r = (u + 0x7FFFu + ((u >> 16) & 1u)) >> 16;  // RNE
  return (unsigned short)r;
}
// e5m2 (bf8) encode: f32 -> f16 (RNE) -> top byte with RNE on bit 7
__device__ __forceinline__ unsigned char f2e5(float x) {
  unsigned short h = __half_as_ushort(__float2half_rn(x));
  return (unsigned char)((h + 0x7Fu + ((h >> 8) & 1u)) >> 8);
}
__device__ __forceinline__ float e52f(unsigned int hs) {
  return __half2float(__ushort_as_half((unsigned short)hs));
}
// decode 4 packed e5m2 (bf8) bytes -> 4 floats
__device__ __forceinline__ void dec4(unsigned int q, float4& o) {
#if __has_builtin(__builtin_amdgcn_cvt_pk_f32_bf8)
  f32x2 lo = __builtin_amdgcn_cvt_pk_f32_bf8((int)q, false);
  f32x2 hi = __builtin_amdgcn_cvt_pk_f32_bf8((int)q, true);
  o.x = lo[0]; o.y = lo[1]; o.z = hi[0]; o.w = hi[1];
#else
  o.x = e52f((q << 8) & 0xFF00u);
  o.y = e52f(q & 0xFF00u);
  o.z = e52f((q >> 8) & 0xFF00u);
  o.w = e52f((q >> 16) & 0xFF00u);
#endif
}
__device__ __forceinline__ float waveSum(float s) {
#pragma unroll
  for (int off = 32; off > 0; off >>= 1) s += __shfl_xor(s, off);
  return s;
}

// x2[n] = sum_c X[n][c]^2 ; one wave per row
__global__ __launch_bounds__(256) void x2_kernel(const float* __restrict__ X,
                                                 float* __restrict__ x2) {
  int wid = threadIdx.x >> 6, lane = threadIdx.x & 63;
  int row = blockIdx.x * 4 + wid;
  float4 v = *(const float4*)(X + (size_t)row * NC + lane * 4);
  float s = v.x * v.x + v.y * v.y + v.z * v.z + v.w * v.w;
  s = waveSum(s);
  if (lane == 0) x2[row] = s;
}

// y2[b][m] = sum_c H[b][c][m]^2 ; grid (72, 4)
__global__ __launch_bounds__(256) void y2_kernel(const float* __restrict__ H,
                                                 float* __restrict__ y2) {
  const int b = blockIdx.y;
  const int m0 = blockIdx.x * 32;
  const int t = threadIdx.x;
  const int ml = t & 31, cg = t >> 5;
  const float* p = H + ((size_t)b * NC + cg) * NM + m0 + ml;
  float s = 0.f;
#pragma unroll 8
  for (int i = 0; i < 32; ++i) {
    float v = p[(size_t)i * 8 * NM];
    s += v * v;
  }
  __shared__ float red[8][33];
  red[cg][ml] = s;
  __syncthreads();
  if (t < 32) {
    float tot = 0.f;
#pragma unroll
    for (int g = 0; g < 8; ++g) tot += red[g][t];
    y2[b * NM + m0 + t] = tot;
  }
}

// Xbf = bf16(X); grid 1024
__global__ __launch_bounds__(256) void prep_xbf(const float* __restrict__ X,
                                                unsigned short* __restrict__ Xbf) {
  size_t i = blockIdx.x * 256 + threadIdx.x;
  float4 xv = *(const float4*)(X + i * 4);
  ushort4 o = {f2bf(xv.x), f2bf(xv.y), f2bf(xv.z), f2bf(xv.w)};
  *(ushort4*)(Xbf + i * 4) = o;
}

// HT[b][m][c] = bf16(H[b][c][m]); grid (72, 8, 4)
__global__ __launch_bounds__(256) void prep_ht(const float* __restrict__ H,
                                               unsigned short* __restrict__ HT) {
  __shared__ unsigned short tile[32][34];
  const int b = blockIdx.z;
  const int mt = blockIdx.x * 32, ct = blockIdx.y * 32;
  const int t = threadIdx.x;
#pragma unroll
  for (int p = 0; p < 4; ++p) {
    int c = ct + p * 8 + (t >> 5);
    tile[t & 31][p * 8 + (t >> 5)] = f2bf(H[((size_t)b * NC + c) * NM + mt + (t & 31)]);
  }
  __syncthreads();
#pragma unroll
  for (int p = 0; p < 4; ++p) {
    int mloc = p * 8 + (t >> 5);
    HT[((size_t)b * NM + mt + mloc) * NC + ct + (t & 31)] = tile[mloc][t & 31];
  }
}

// XqT[c][n] = e5m2(X[n][c]) ; b-independent, 1 MB. grid (128, 8)
__global__ __launch_bounds__(256) void prep_xq(const float* __restrict__ X,
                                               unsigned char* __restrict__ XqT) {
  __shared__ unsigned char tile[32][36];
  const int nt = blockIdx.x * 32, ct = blockIdx.y * 32;
  const int t = threadIdx.x;
#pragma unroll
  for (int p = 0; p < 4; ++p) {
    int nloc = p * 8 + (t >> 5);
    tile[nloc][t & 31] = f2e5(X[(size_t)(nt + nloc) * NC + ct + (t & 31)]);
  }
  __syncthreads();
  int cl = t >> 3, seg = t & 7;
  uchar4 o = {tile[seg * 4 + 0][cl], tile[seg * 4 + 1][cl],
              tile[seg * 4 + 2][cl], tile[seg * 4 + 3][cl]};
  *(uchar4*)(XqT + (size_t)(ct + cl) * NN + nt + seg * 4) = o;
}

// usum slot0 = 1.0 (seed), u slot0 = A_VAL, nc = 1
__global__ __launch_bounds__(256) void init_kernel(float* __restrict__ usum0,
                                                   float* __restrict__ u0,
                                                   int* __restrict__ nc) {
  int gid = blockIdx.x * 256 + threadIdx.x;  // grid 64 -> 16384
  usum0[gid] = 1.0f;
  u0[gid] = A_VAL;
  if (gid < 8) nc[gid] = 1;
}

// MFMA cost kernel: tile 128n x 128m; writes ONLY KT[b][m][n] (bf16).
__global__ __launch_bounds__(256) void cost_k_mfma(
    const unsigned short* __restrict__ Xbf, const unsigned short* __restrict__ HT,
    const float* __restrict__ x2, const float* __restrict__ y2,
    unsigned short* __restrict__ KT) {
  __shared__ __align__(16) unsigned short smem[128 * 88];
  const int b = blockIdx.z;
  const int n0 = blockIdx.x * 128, m0 = blockIdx.y * 128;
  const int t = threadIdx.x, l = t & 63, w = t >> 6;
  const int wn = (w >> 1) * 64, wm = (w & 1) * 64;
  const int fr = l & 15, fq = l >> 4;
  f32x4 zero = {0.f, 0.f, 0.f, 0.f};
  f32x4 acc[4][4];
#pragma unroll
  for (int i = 0; i < 4; ++i)
#pragma unroll
    for (int j = 0; j < 4; ++j) acc[i][j] = zero;

  for (int c0 = 0; c0 < NC; c0 += 32) {
#pragma unroll
    for (int i = 0; i < 2; ++i) {
      int idx = t + i * 256;
      int row = idx >> 2, ck = idx & 3;
      float4 av = *(const float4*)(Xbf + (size_t)(n0 + row) * NC + c0 + ck * 8);
      *(float4*)(&smem[row * 44 + ck * 8]) = av;
      float4 bv = *(const float4*)(HT + ((size_t)b * NM + m0 + row) * NC + c0 + ck * 8);
      *(float4*)(&smem[5632 + row * 44 + ck * 8]) = bv;
    }
    __syncthreads();
    bf16x8 a[4], bb[4];
#pragma unroll
    for (int f = 0; f < 4; ++f) {
      a[f] = *(const bf16x8*)(&smem[(wn + f * 16 + fr) * 44 + fq * 8]);
      bb[f] = *(const bf16x8*)(&smem[5632 + (wm + f * 16 + fr) * 44 + fq * 8]);
    }
#pragma unroll
    for (int i = 0; i < 4; ++i)
#pragma unroll
      for (int j = 0; j < 4; ++j)
        acc[i][j] = __builtin_amdgcn_mfma_f32_16x16x32_bf16(a[i], bb[j], acc[i][j], 0, 0, 0);
    __syncthreads();
  }
  float x2a[4][4];
#pragma unroll
  for (int fi = 0; fi < 4; ++fi) {
    float4 xv = *(const float4*)(x2 + n0 + wn + fi * 16 + fq * 4);
    x2a[fi][0] = xv.x; x2a[fi][1] = xv.y; x2a[fi][2] = xv.z; x2a[fi][3] = xv.w;
  }
  float y2a[4];
#pragma unroll
  for (int fj = 0; fj < 4; ++fj) y2a[fj] = y2[b * NM + m0 + wm + fj * 16 + fr];
  unsigned short kb[4][4][4];
#pragma unroll
  for (int fi = 0; fi < 4; ++fi)
#pragma unroll
    for (int fj = 0; fj < 4; ++fj)
#pragma unroll
      for (int r = 0; r < 4; ++r) {
        float cost = fmaxf(x2a[fi][r] + y2a[fj] - 2.0f * acc[fi][fj][r], 0.0f);
        kb[fi][fj][r] = f2bf(__expf(-cost * REG_INV));
      }
  // KT: two m-chunks (64 rows x 128 n), swizzled stage -> coalesced stores
#pragma unroll
  for (int h = 0; h < 2; ++h) {
    __syncthreads();
    if ((w & 1) == h) {
#pragma unroll
      for (int fj = 0; fj < 4; ++fj) {
        int rr = fj * 16 + fr;
#pragma unroll
        for (int fi = 0; fi < 4; ++fi) {
          int cc = wn + fi * 16 + fq * 4;
          ushort4 kt4 = {kb[fi][fj][0], kb[fi][fj][1], kb[fi][fj][2], kb[fi][fj][3]};
          *(ushort4*)&smem[rr * 136 + (cc ^ ((rr & 7) << 3))] = kt4;
        }
      }
    }
    __syncthreads();
#pragma unroll
    for (int p = 0; p < 4; ++p) {
      int row = p * 16 + (t >> 4), co = (t & 15) * 8;
      *(float4*)(KT + ((size_t)b * NM + m0 + h * 64 + row) * NN + n0 + co) =
          *(const float4*)&smem[row * 136 + (co ^ ((row & 7) << 3))];
    }
  }
}

// Per-KT-row (column of K) max + e5m2 quantization into separate fp8 buffer.
// K~T[m][n] = KT[m][n] * c[m], c = 32768/colmax. (scale cancels downstream)
__global__ __launch_bounds__(256) void requant_kernel(
    const unsigned short* __restrict__ KT, unsigned char* __restrict__ K8T) {
  const int row = blockIdx.x;  // 0..9215 (= b*NM + m)
  const int t = threadIdx.x, l = t & 63, wv = t >> 6;
  const unsigned short* src = KT + (size_t)row * NN + t * 16;
  float4 a0 = *(const float4*)(src);
  float4 a1 = *(const float4*)(src + 8);
  const unsigned short* s0 = (const unsigned short*)&a0;
  const unsigned short* s1 = (const unsigned short*)&a1;
  float mx = 0.f;
#pragma unroll
  for (int j = 0; j < 8; ++j)
    mx = fmaxf(mx, fmaxf(bf2f(s0[j]), bf2f(s1[j])));
#pragma unroll
  for (int off = 32; off > 0; off >>= 1) mx = fmaxf(mx, __shfl_xor(mx, off));
  __shared__ float wmx[4];
  if (l == 0) wmx[wv] = mx;
  __syncthreads();
  mx = fmaxf(fmaxf(wmx[0], wmx[1]), fmaxf(wmx[2], wmx[3]));
  float c = fminf(32768.0f / mx, 1e38f);
  unsigned int o[4] = {0, 0, 0, 0};
#pragma unroll
  for (int j = 0; j < 8; ++j) {
    o[j >> 2] |= (unsigned int)f2e5(bf2f(s0[j]) * c) << ((j & 3) * 8);
    o[2 + (j >> 2)] |= (unsigned int)f2e5(bf2f(s1[j]) * c) << ((j & 3) * 8);
  }
  uint4 ov = {o[0], o[1], o[2], o[3]};
  *(uint4*)(K8T + (size_t)row * NN + t * 16) = ov;
}

// Kernel A: finalize u (omega=1.25), then v~ row dots over K~T. grid (192, 4).
__global__ __launch_bounds__(256) void vrow_kernel(
    const unsigned char* __restrict__ K8T, const float* __restrict__ usumR,
    float* __restrict__ usumZ, const float* __restrict__ uR,
    float* __restrict__ uW, float* __restrict__ uF, float* __restrict__ vB,
    const int* __restrict__ ncG, int* __restrict__ ncS, int force) {
  const int b = blockIdx.y, bx = blockIdx.x;
  const int t = threadIdx.x, l = t & 63, wv = t >> 6;
  if (bx == 0 && t == 0) ncS[b] = 0;  // pre-gate zero (sticky-done)
  if (ncG[b] == 0) return;
  __shared__ __align__(16) float uS[NN];
  int flag = force;
#pragma unroll
  for (int jj = 0; jj < 16; ++jj) {
    int i = jj * 256 + t;
    float us = usumR[b * NN + i];
    float uo = uR[b * NN + i];
    float ut = A_VAL / us;
    float r = ut / uo;
    float un = uo * r * sqrtf(sqrtf(r));  // r^1.25
    uS[i] = un;
    if (bx == 0) {
      uW[b * NN + i] = un;
      uF[b * NN + i] = un;
      if (fabsf(ut - uo) > EPS_CONV * uo) flag = 1;
    }
    if (bx == 1) usumZ[b * NN + i] = 0.f;
  }
  __syncthreads();
  if (bx == 0 && flag) ncS[b] = 1;  // ordered after t0's zero by the barrier
  const unsigned char* KTb = K8T + (size_t)(b * NM + bx * 12) * NN;
#pragma unroll 1
  for (int rr = 0; rr < 3; ++rr) {
    int row = wv * 3 + rr;  // 0..11
    const unsigned int* Kp = (const unsigned int*)(KTb + (size_t)row * NN);
    float s = 0.f;
#pragma unroll
    for (int p = 0; p < 16; ++p) {
      unsigned int q = Kp[l + 64 * p];
      float4 d;
      dec4(q, d);
      float4 uu = ((const float4*)uS)[l + 64 * p];
      s += d.x * uu.x + d.y * uu.y + d.z * uu.z + d.w * uu.w;
    }
    s = waveSum(s);
    if (l == 0) vB[b * NM + bx * 12 + row] = B_VAL / s;
  }
}

// Kernel B: tiled column partials: usumA[n] += sum_m K~T[m][n]*v~[m].
// grid (16, 8, 4); 256 atomics/block.
__global__ __launch_bounds__(256) void ucol_kernel(
    const unsigned char* __restrict__ K8T, const float* __restrict__ vB,
    float* __restrict__ usumA, const int* __restrict__ ncG) {
  const int b = blockIdx.z;
  if (ncG[b] == 0) return;
  const int nch = blockIdx.x;  // 0..15 (256 n)
  const int mch = blockIdx.y;  // 0..7  (288 m)
  const int t = threadIdx.x, l = t & 63, wv = t >> 6;
  __shared__ float vS[288];
  __shared__ __align__(16) float red[4][64][4];
  for (int i = t; i < 288; i += 256) vS[i] = vB[b * NM + mch * 288 + i];
  __syncthreads();
  const unsigned char* Kp =
      K8T + (size_t)(b * NM + mch * 288) * NN + nch * 256 + l * 4;
  float4 acc = {0.f, 0.f, 0.f, 0.f};
#pragma unroll 8
  for (int i = 0; i < 72; ++i) {
    int m = i * 4 + wv;
    unsigned int q = *(const unsigned int*)(Kp + (size_t)m * NN);
    float4 d;
    dec4(q, d);
    float vv = vS[m];
    acc.x += d.x * vv;
    acc.y += d.y * vv;
    acc.z += d.z * vv;
    acc.w += d.w * vv;
  }
  *(float4*)red[wv][l] = acc;
  __syncthreads();
  if (wv == 0) {
    float4 a0 = *(float4*)red[0][l];
    float4 a1 = *(float4*)red[1][l];
    float4 a2 = *(float4*)red[2][l];
    float4 a3 = *(float4*)red[3][l];
    float* dst = usumA + (size_t)b * NN + nch * 256 + l * 4;
    atomicAdd(dst + 0, a0.x + a1.x + a2.x + a3.x);
    atomicAdd(dst + 1, a0.y + a1.y + a2.y + a3.y);
    atomicAdd(dst + 2, a0.z + a1.z + a2.z + a3.z);
    atomicAdd(dst + 3, a0.w + a1.w + a2.w + a3.w);
  }
}

// requant2: K8Tu[m][n] = e5m2(dec(K~T[m][n]) * u[n] * c2[m]), c2 = 32768/rowmax.
// c2inv[m] = rowmax/32768 folds into epilogue. grid (2304, 4), block 256.
__global__ __launch_bounds__(256) void requant2_kernel(
    const unsigned char* __restrict__ K8T, const float* __restrict__ uF,
    unsigned char* __restrict__ K8Tu, float* __restrict__ c2inv) {
  const int m = blockIdx.x, b = blockIdx.y;
  const int t = threadIdx.x, l = t & 63, wv = t >> 6;
  __shared__ float uS[NN];
  for (int i = t; i < NN; i += 256) uS[i] = uF[b * NN + i];
  __syncthreads();
  uint4 q4 = *(const uint4*)(K8T + (size_t)(b * NM + m) * NN + t * 16);
  float p[16];
  float4 d;
  dec4(q4.x, d); p[0] = d.x; p[1] = d.y; p[2] = d.z; p[3] = d.w;
  dec4(q4.y, d); p[4] = d.x; p[5] = d.y; p[6] = d.z; p[7] = d.w;
  dec4(q4.z, d); p[8] = d.x; p[9] = d.y; p[10] = d.z; p[11] = d.w;
  dec4(q4.w, d); p[12] = d.x; p[13] = d.y; p[14] = d.z; p[15] = d.w;
  float mx = 0.f;
#pragma unroll
  for (int j = 0; j < 16; ++j) {
    p[j] *= uS[16 * t + j];
    mx = fmaxf(mx, p[j]);
  }
#pragma unroll
  for (int off = 32; off > 0; off >>= 1) mx = fmaxf(mx, __shfl_xor(mx, off));
  __shared__ float wmx[4];
  if (l == 0) wmx[wv] = mx;
  __syncthreads();
  mx = fmaxf(fmaxf(wmx[0], wmx[1]), fmaxf(wmx[2], wmx[3]));
  float c2 = 32768.0f / mx;
  if (t == 0) c2inv[(size_t)b * NM + m] = mx * (1.0f / 32768.0f);
  unsigned int o[4] = {0, 0, 0, 0};
#pragma unroll
  for (int j = 0; j < 16; ++j)
    o[j >> 2] |= (unsigned int)f2e5(p[j] * c2) << ((j & 3) * 8);
  uint4 ov = {o[0], o[1], o[2], o[3]};
  *(uint4*)(K8Tu + (size_t)(b * NM + m) * NN + t * 16) = ov;
}

// XT partial[kh] = v~[m]*c2inv[m] * sum_n XqT[c][n]*K8Tu[m][n] via NATIVE bf8
// MFMA (no decode). Split-K=2: grid (4, 36, 8). Tile 64c x 64m, BK=64.
__global__ __launch_bounds__(256) void xspace_bf8(
    const unsigned char* __restrict__ XqT, const unsigned char* __restrict__ K8Tu,
    const float* __restrict__ vB, const float* __restrict__ c2inv,
    float* __restrict__ XT0, float* __restrict__ XT1) {
  __shared__ __align__(16) unsigned char As[64][80];
  __shared__ __align__(16) unsigned char Bs[64][80];
  const int b = blockIdx.z & 3, kh = blockIdx.z >> 2;
  const int c0 = blockIdx.x * 64, m0 = blockIdx.y * 64;
  const int t = threadIdx.x, l = t & 63, w = t >> 6;
  const int wc = (w >> 1) * 32, wm = (w & 1) * 32;
  const int fr = l & 15, fq = l >> 4;
  f32x4 zero = {0.f, 0.f, 0.f, 0.f};
  f32x4 acc[2][2];
#pragma unroll
  for (int i = 0; i < 2; ++i)
#pragma unroll
    for (int j = 0; j < 2; ++j) acc[i][j] = zero;

  const int srow = t >> 2, sseg = t & 3;  // 64 rows x 4 x 16B
  const int kbeg = kh * 2048;
  for (int k0 = kbeg; k0 < kbeg + 2048; k0 += 64) {
    *(uint4*)&As[srow][sseg * 16] =
        *(const uint4*)(XqT + (size_t)(c0 + srow) * NN + k0 + sseg * 16);
    *(uint4*)&Bs[srow][sseg * 16] =
        *(const uint4*)(K8Tu + ((size_t)b * NM + m0 + srow) * NN + k0 + sseg * 16);
    __syncthreads();
    long long a[2][2], bb[2][2];
#pragma unroll
    for (int f = 0; f < 2; ++f)
#pragma unroll
      for (int ks = 0; ks < 2; ++ks) {
        a[f][ks] = *(const long long*)&As[wc + f * 16 + fr][ks * 32 + fq * 8];
        bb[f][ks] = *(const long long*)&Bs[wm + f * 16 + fr][ks * 32 + fq * 8];
      }
#pragma unroll
    for (int ks = 0; ks < 2; ++ks)
#pragma unroll
      for (int i = 0; i < 2; ++i)
#pragma unroll
        for (int j = 0; j < 2; ++j)
          acc[i][j] = __builtin_amdgcn_mfma_f32_16x16x32_bf8_bf8(
              a[i][ks], bb[j][ks], acc[i][j], 0, 0, 0);
    __syncthreads();
  }
  float* XTo = kh ? XT1 : XT0;
#pragma unroll
  for (int fj = 0; fj < 2; ++fj) {
    int m = m0 + wm + fj * 16 + fr;
    float vm = vB[(size_t)b * NM + m] * c2inv[(size_t)b * NM + m];
#pragma unroll
    for (int fi = 0; fi < 2; ++fi) {
      int cb = c0 + wc + fi * 16 + fq * 4;
#pragma unroll
      for (int r = 0; r < 4; ++r)
        XTo[((size_t)b * NC + cb + r) * NM + m] = vm * acc[fi][fj][r];
    }
  }
}

// out_aligned = H + alpha*(XT0+XT1); out_feat = XT0+XT1; partial (H-XT)^2 sums
__global__ __launch_bounds__(256) void finalize_kernel(
    const float* __restrict__ H, const float* __restrict__ XT0,
    const float* __restrict__ XT1, float* __restrict__ out_aligned,
    float* __restrict__ out_feat, float* __restrict__ partials) {
  const int t = threadIdx.x;
  float s = 0.f;
  for (int i = blockIdx.x * 256 + t; i < OUT_ELEMS / 4; i += 1024 * 256) {
    float4 h = *(const float4*)(H + (size_t)i * 4);
    float4 xa = *(const float4*)(XT0 + (size_t)i * 4);
    float4 xb = *(const float4*)(XT1 + (size_t)i * 4);
    float4 x;
    x.x = xa.x + xb.x;
    x.y = xa.y + xb.y;
    x.z = xa.z + xb.z;
    x.w = xa.w + xb.w;
    float4 o;
    o.x = h.x + ALPHA_C * x.x;
    o.y = h.y + ALPHA_C * x.y;
    o.z = h.z + ALPHA_C * x.z;
    o.w = h.w + ALPHA_C * x.w;
    *(float4*)(out_aligned + (size_t)i * 4) = o;
    out_feat[(size_t)i * 4 + 0] = x.x;  // dest misaligned by 1 float -> scalar
    out_feat[(size_t)i * 4 + 1] = x.y;
    out_feat[(size_t)i * 4 + 2] = x.z;
    out_feat[(size_t)i * 4 + 3] = x.w;
    float dx = h.x - x.x, dy = h.y - x.y, dz = h.z - x.z, dw = h.w - x.w;
    s += dx * dx + dy * dy + dz * dz + dw * dw;
  }
  s = waveSum(s);
  __shared__ float ws_[4];
  if ((t & 63) == 0) ws_[t >> 6] = s;
  __syncthreads();
  if (t == 0) partials[blockIdx.x] = ws_[0] + ws_[1] + ws_[2] + ws_[3];
}

__global__ __launch_bounds__(256) void lot_kernel(
    const float* __restrict__ partials, float* __restrict__ out_lot) {
  float s = 0.f;
  for (int i = threadIdx.x; i < 1024; i += 256) s += partials[i];
  s = waveSum(s);
  __shared__ float ws_[4];
  if ((threadIdx.x & 63) == 0) ws_[threadIdx.x >> 6] = s;
  __syncthreads();
  if (threadIdx.x == 0)
    out_lot[0] = (ws_[0] + ws_[1] + ws_[2] + ws_[3]) / (float)OUT_ELEMS;
}

extern "C" void kernel_launch(void* const* d_in, const int* in_sizes, int n_in,
                              void* d_out, int out_size, void* d_ws,
                              size_t ws_size, hipStream_t stream) {
  const float* X = (const float*)d_in[0];  // sc (4096,256)
  const float* H = (const float*)d_in[1];  // h_spot (4,256,48,48)
  float* out = (float*)d_out;
  char* ws = (char*)d_ws;

  // workspace layout (bytes)
  unsigned short* KT = (unsigned short*)(ws);           // 75,497,472 (dead after requant1)
  unsigned char* K8Tu = (unsigned char*)(ws);           // 37,748,736 (aliases KT; written by requant2)
  unsigned char* K8T = (unsigned char*)(ws + 75497472); // 37,748,736 (fp8 loop matrix)
  float* XT0 = (float*)(ws + 113246208);                // 9,437,184
  // aliases inside XT0 region (dead before xspace writes):
  unsigned short* Xbf = (unsigned short*)(ws + 113246208);           // 2,097,152
  unsigned short* HT = (unsigned short*)(ws + 113246208 + 2097152);  // 4,718,592
  float* usum = (float*)(ws + 122683392);   // 2 slots x 65,536
  float* u = (float*)(ws + 122814464);      // 2 slots x 65,536
  float* uF = (float*)(ws + 122945536);     // 65,536
  float* vB = (float*)(ws + 123011072);     // 36,864
  float* x2 = (float*)(ws + 123047936);     // 16,384
  float* y2 = (float*)(ws + 123064320);     // 36,864
  int* nc = (int*)(ws + 123101184);         // 32
  float* partials = (float*)(ws + 123101216);  // 4,096
  float* c2inv = (float*)(ws + 123105312);  // 36,864 -> ends 123,142,176
  unsigned char* XqT = (unsigned char*)(ws + 125829120);  // 1,048,576
  float* XT1 = (float*)(ws + 134217728);    // 9,437,184 -> ends 143,654,912
  if (ws_size < (size_t)143654912) return;

  x2_kernel<<<1024, 256, 0, stream>>>(X, x2);
  y2_kernel<<<dim3(72, 4), 256, 0, stream>>>(H, y2);
  prep_xbf<<<1024, 256, 0, stream>>>(X, Xbf);
  prep_ht<<<dim3(72, 8, 4), 256, 0, stream>>>(H, HT);
  prep_xq<<<dim3(128, 8), 256, 0, stream>>>(X, XqT);
  cost_k_mfma<<<dim3(32, 18, 4), 256, 0, stream>>>(Xbf, HT, x2, y2, KT);
  requant_kernel<<<9216, 256, 0, stream>>>(KT, K8T);
  init_kernel<<<64, 256, 0, stream>>>(usum, u, nc);
  for (int it = 0; it < MAX_IT; ++it) {
    const int p = it & 1, q = 1 - p;
    vrow_kernel<<<dim3(192, 4), 256, 0, stream>>>(
        K8T, usum + (size_t)p * 4 * NN, usum + (size_t)q * 4 * NN,
        u + (size_t)p * 4 * NN, u + (size_t)q * 4 * NN, uF, vB,
        nc + q * 4, nc + p * 4, it == 0 ? 1 : 0);
    ucol_kernel<<<dim3(16, 8, 4), 256, 0, stream>>>(
        K8T, vB, usum + (size_t)q * 4 * NN, nc + q * 4);
  }
  requant2_kernel<<<dim3(2304, 4), 256, 0, stream>>>(K8T, uF, K8Tu, c2inv);
  xspace_bf8<<<dim3(4, 36, 8), 256, 0, stream>>>(XqT, K8Tu, vB, c2inv, XT0, XT1);
  finalize_kernel<<<1024, 256, 0, stream>>>(H, XT0, XT1, out,
                                            out + OUT_ELEMS + 1, partials);
  lot_kernel<<<1, 256, 0, stream>>>(partials, out + OUT_ELEMS);
}

// Round 15
// 384.764 us; speedup vs baseline: 1.9765x; 1.2705x over previous
//
#include <hip/hip_runtime.h>
#include <hip/hip_fp16.h>

#define NN 4096
#define NM 2304
#define NC 256
#define OUT_ELEMS 2359296  // 4*256*48*48
#define MAX_IT 10

static constexpr float REG_INV = 0.1f;      // 1/REG
static constexpr float A_VAL = 1.0f / 4096.0f;
static constexpr float B_VAL = 1.0f / 2304.0f;
static constexpr float ALPHA_C = 0.001f;
static constexpr float EPS_CONV = 1e-4f;  // residual << fp8 error
static constexpr float S_Q = 6144.0f;     // global A-operand scale (6144*max|X| < 57344)
// over-relaxation u' = u*(ut/u)^1.25 via r*sqrt(sqrt(r)); omega=1.25 ~ SOR-optimal

typedef __attribute__((ext_vector_type(8))) short bf16x8;
typedef __attribute__((ext_vector_type(4))) float f32x4;
typedef __attribute__((ext_vector_type(2))) float f32x2;

__device__ __forceinline__ float bf2f(unsigned short h) {
  return __uint_as_float(((unsigned int)h) << 16);
}
__device__ __forceinline__ unsigned short f2bf(float f) {
  unsigned int u = __float_as_uint(f);
  unsigned int r = (u + 0x7FFFu + ((u >> 16) & 1u)) >> 16;  // RNE
  return (unsigned short)r;
}
// e5m2 (bf8) encode: f32 -> f16 (RNE) -> top byte with RNE on bit 7
__device__ __forceinline__ unsigned char f2e5(float x) {
  unsigned short h = __half_as_ushort(__float2half_rn(x));
  return (unsigned char)((h + 0x7Fu + ((h >> 8) & 1u)) >> 8);
}
__device__ __forceinline__ float e52f(unsigned int hs) {
  return __half2float(__ushort_as_half((unsigned short)hs));
}
// decode 4 packed e5m2 (bf8) bytes -> 4 floats
__device__ __forceinline__ void dec4(unsigned int q, float4& o) {
#if __has_builtin(__builtin_amdgcn_cvt_pk_f32_bf8)
  f32x2 lo = __builtin_amdgcn_cvt_pk_f32_bf8((int)q, false);
  f32x2 hi = __builtin_amdgcn_cvt_pk_f32_bf8((int)q, true);
  o.x = lo[0]; o.y = lo[1]; o.z = hi[0]; o.w = hi[1];
#else
  o.x = e52f((q << 8) & 0xFF00u);
  o.y = e52f(q & 0xFF00u);
  o.z = e52f((q >> 8) & 0xFF00u);
  o.w = e52f((q >> 16) & 0xFF00u);
#endif
}
__device__ __forceinline__ float waveSum(float s) {
#pragma unroll
  for (int off = 32; off > 0; off >>= 1) s += __shfl_xor(s, off);
  return s;
}

// x2[n] = sum_c X[n][c]^2 ; one wave per row
__global__ __launch_bounds__(256) void x2_kernel(const float* __restrict__ X,
                                                 float* __restrict__ x2) {
  int wid = threadIdx.x >> 6, lane = threadIdx.x & 63;
  int row = blockIdx.x * 4 + wid;
  float4 v = *(const float4*)(X + (size_t)row * NC + lane * 4);
  float s = v.x * v.x + v.y * v.y + v.z * v.z + v.w * v.w;
  s = waveSum(s);
  if (lane == 0) x2[row] = s;
}

// y2[b][m] = sum_c H[b][c][m]^2 ; grid (72, 4)
__global__ __launch_bounds__(256) void y2_kernel(const float* __restrict__ H,
                                                 float* __restrict__ y2) {
  const int b = blockIdx.y;
  const int m0 = blockIdx.x * 32;
  const int t = threadIdx.x;
  const int ml = t & 31, cg = t >> 5;
  const float* p = H + ((size_t)b * NC + cg) * NM + m0 + ml;
  float s = 0.f;
#pragma unroll 8
  for (int i = 0; i < 32; ++i) {
    float v = p[(size_t)i * 8 * NM];
    s += v * v;
  }
  __shared__ float red[8][33];
  red[cg][ml] = s;
  __syncthreads();
  if (t < 32) {
    float tot = 0.f;
#pragma unroll
    for (int g = 0; g < 8; ++g) tot += red[g][t];
    y2[b * NM + m0 + t] = tot;
  }
}

// Xbf = bf16(X); grid 1024
__global__ __launch_bounds__(256) void prep_xbf(const float* __restrict__ X,
                                                unsigned short* __restrict__ Xbf) {
  size_t i = blockIdx.x * 256 + threadIdx.x;
  float4 xv = *(const float4*)(X + i * 4);
  ushort4 o = {f2bf(xv.x), f2bf(xv.y), f2bf(xv.z), f2bf(xv.w)};
  *(ushort4*)(Xbf + i * 4) = o;
}

// HT[b][m][c] = bf16(H[b][c][m]); grid (72, 8, 4)
__global__ __launch_bounds__(256) void prep_ht(const float* __restrict__ H,
                                               unsigned short* __restrict__ HT) {
  __shared__ unsigned short tile[32][34];
  const int b = blockIdx.z;
  const int mt = blockIdx.x * 32, ct = blockIdx.y * 32;
  const int t = threadIdx.x;
#pragma unroll
  for (int p = 0; p < 4; ++p) {
    int c = ct + p * 8 + (t >> 5);
    tile[t & 31][p * 8 + (t >> 5)] = f2bf(H[((size_t)b * NC + c) * NM + mt + (t & 31)]);
  }
  __syncthreads();
#pragma unroll
  for (int p = 0; p < 4; ++p) {
    int mloc = p * 8 + (t >> 5);
    HT[((size_t)b * NM + mt + mloc) * NC + ct + (t & 31)] = tile[mloc][t & 31];
  }
}

// umax[b] = max_n uF[b][n]; grid 4
__global__ __launch_bounds__(256) void umax_kernel(const float* __restrict__ uF,
                                                   float* __restrict__ umax) {
  const int b = blockIdx.x, t = threadIdx.x, l = t & 63, wv = t >> 6;
  float mx = 0.f;
  for (int i = t; i < NN; i += 256) mx = fmaxf(mx, uF[b * NN + i]);
#pragma unroll
  for (int off = 32; off > 0; off >>= 1) mx = fmaxf(mx, __shfl_xor(mx, off));
  __shared__ float wm[4];
  if (l == 0) wm[wv] = mx;
  __syncthreads();
  if (t == 0) umax[b] = fmaxf(fmaxf(wm[0], wm[1]), fmaxf(wm[2], wm[3]));
}

// XquT[b][c][n] = e5m2(S_Q/umax[b] * u[n] * X[n][c]); grid (128, 8, 4)
__global__ __launch_bounds__(256) void prep_xqu(const float* __restrict__ X,
                                                const float* __restrict__ uF,
                                                const float* __restrict__ umax,
                                                unsigned char* __restrict__ XquT) {
  __shared__ unsigned char tile[32][36];
  const int b = blockIdx.z;
  const int nt = blockIdx.x * 32, ct = blockIdx.y * 32;
  const int t = threadIdx.x;
  const float s = S_Q / umax[b];
#pragma unroll
  for (int p = 0; p < 4; ++p) {
    int nloc = p * 8 + (t >> 5);
    float uu = s * uF[b * NN + nt + nloc];
    tile[nloc][t & 31] = f2e5(uu * X[(size_t)(nt + nloc) * NC + ct + (t & 31)]);
  }
  __syncthreads();
  int cl = t >> 3, seg = t & 7;
  uchar4 o = {tile[seg * 4 + 0][cl], tile[seg * 4 + 1][cl],
              tile[seg * 4 + 2][cl], tile[seg * 4 + 3][cl]};
  *(uchar4*)(XquT + ((size_t)b * NC + ct + cl) * NN + nt + seg * 4) = o;
}

// usum slot0 = 1.0 (seed), u slot0 = A_VAL, nc = 1
__global__ __launch_bounds__(256) void init_kernel(float* __restrict__ usum0,
                                                   float* __restrict__ u0,
                                                   int* __restrict__ nc) {
  int gid = blockIdx.x * 256 + threadIdx.x;  // grid 64 -> 16384
  usum0[gid] = 1.0f;
  u0[gid] = A_VAL;
  if (gid < 8) nc[gid] = 1;
}

// MFMA cost kernel: tile 128n x 128m; writes ONLY KT[b][m][n] (bf16).
__global__ __launch_bounds__(256) void cost_k_mfma(
    const unsigned short* __restrict__ Xbf, const unsigned short* __restrict__ HT,
    const float* __restrict__ x2, const float* __restrict__ y2,
    unsigned short* __restrict__ KT) {
  __shared__ __align__(16) unsigned short smem[128 * 88];
  const int b = blockIdx.z;
  const int n0 = blockIdx.x * 128, m0 = blockIdx.y * 128;
  const int t = threadIdx.x, l = t & 63, w = t >> 6;
  const int wn = (w >> 1) * 64, wm = (w & 1) * 64;
  const int fr = l & 15, fq = l >> 4;
  f32x4 zero = {0.f, 0.f, 0.f, 0.f};
  f32x4 acc[4][4];
#pragma unroll
  for (int i = 0; i < 4; ++i)
#pragma unroll
    for (int j = 0; j < 4; ++j) acc[i][j] = zero;

  for (int c0 = 0; c0 < NC; c0 += 32) {
#pragma unroll
    for (int i = 0; i < 2; ++i) {
      int idx = t + i * 256;
      int row = idx >> 2, ck = idx & 3;
      float4 av = *(const float4*)(Xbf + (size_t)(n0 + row) * NC + c0 + ck * 8);
      *(float4*)(&smem[row * 44 + ck * 8]) = av;
      float4 bv = *(const float4*)(HT + ((size_t)b * NM + m0 + row) * NC + c0 + ck * 8);
      *(float4*)(&smem[5632 + row * 44 + ck * 8]) = bv;
    }
    __syncthreads();
    bf16x8 a[4], bb[4];
#pragma unroll
    for (int f = 0; f < 4; ++f) {
      a[f] = *(const bf16x8*)(&smem[(wn + f * 16 + fr) * 44 + fq * 8]);
      bb[f] = *(const bf16x8*)(&smem[5632 + (wm + f * 16 + fr) * 44 + fq * 8]);
    }
#pragma unroll
    for (int i = 0; i < 4; ++i)
#pragma unroll
      for (int j = 0; j < 4; ++j)
        acc[i][j] = __builtin_amdgcn_mfma_f32_16x16x32_bf16(a[i], bb[j], acc[i][j], 0, 0, 0);
    __syncthreads();
  }
  float x2a[4][4];
#pragma unroll
  for (int fi = 0; fi < 4; ++fi) {
    float4 xv = *(const float4*)(x2 + n0 + wn + fi * 16 + fq * 4);
    x2a[fi][0] = xv.x; x2a[fi][1] = xv.y; x2a[fi][2] = xv.z; x2a[fi][3] = xv.w;
  }
  float y2a[4];
#pragma unroll
  for (int fj = 0; fj < 4; ++fj) y2a[fj] = y2[b * NM + m0 + wm + fj * 16 + fr];
  unsigned short kb[4][4][4];
#pragma unroll
  for (int fi = 0; fi < 4; ++fi)
#pragma unroll
    for (int fj = 0; fj < 4; ++fj)
#pragma unroll
      for (int r = 0; r < 4; ++r) {
        float cost = fmaxf(x2a[fi][r] + y2a[fj] - 2.0f * acc[fi][fj][r], 0.0f);
        kb[fi][fj][r] = f2bf(__expf(-cost * REG_INV));
      }
  // KT: two m-chunks (64 rows x 128 n), swizzled stage -> coalesced stores
#pragma unroll
  for (int h = 0; h < 2; ++h) {
    __syncthreads();
    if ((w & 1) == h) {
#pragma unroll
      for (int fj = 0; fj < 4; ++fj) {
        int rr = fj * 16 + fr;
#pragma unroll
        for (int fi = 0; fi < 4; ++fi) {
          int cc = wn + fi * 16 + fq * 4;
          ushort4 kt4 = {kb[fi][fj][0], kb[fi][fj][1], kb[fi][fj][2], kb[fi][fj][3]};
          *(ushort4*)&smem[rr * 136 + (cc ^ ((rr & 7) << 3))] = kt4;
        }
      }
    }
    __syncthreads();
#pragma unroll
    for (int p = 0; p < 4; ++p) {
      int row = p * 16 + (t >> 4), co = (t & 15) * 8;
      *(float4*)(KT + ((size_t)b * NM + m0 + h * 64 + row) * NN + n0 + co) =
          *(const float4*)&smem[row * 136 + (co ^ ((row & 7) << 3))];
    }
  }
}

// Per-KT-row (column of K) max + e5m2 quantization into separate fp8 buffer.
// K~T[m][n] = KT[m][n] * c[m], c = 32768/colmax. (scale cancels downstream)
__global__ __launch_bounds__(256) void requant_kernel(
    const unsigned short* __restrict__ KT, unsigned char* __restrict__ K8T) {
  const int row = blockIdx.x;  // 0..9215 (= b*NM + m)
  const int t = threadIdx.x, l = t & 63, wv = t >> 6;
  const unsigned short* src = KT + (size_t)row * NN + t * 16;
  float4 a0 = *(const float4*)(src);
  float4 a1 = *(const float4*)(src + 8);
  const unsigned short* s0 = (const unsigned short*)&a0;
  const unsigned short* s1 = (const unsigned short*)&a1;
  float mx = 0.f;
#pragma unroll
  for (int j = 0; j < 8; ++j)
    mx = fmaxf(mx, fmaxf(bf2f(s0[j]), bf2f(s1[j])));
#pragma unroll
  for (int off = 32; off > 0; off >>= 1) mx = fmaxf(mx, __shfl_xor(mx, off));
  __shared__ float wmx[4];
  if (l == 0) wmx[wv] = mx;
  __syncthreads();
  mx = fmaxf(fmaxf(wmx[0], wmx[1]), fmaxf(wmx[2], wmx[3]));
  float c = fminf(32768.0f / mx, 1e38f);
  unsigned int o[4] = {0, 0, 0, 0};
#pragma unroll
  for (int j = 0; j < 8; ++j) {
    o[j >> 2] |= (unsigned int)f2e5(bf2f(s0[j]) * c) << ((j & 3) * 8);
    o[2 + (j >> 2)] |= (unsigned int)f2e5(bf2f(s1[j]) * c) << ((j & 3) * 8);
  }
  uint4 ov = {o[0], o[1], o[2], o[3]};
  *(uint4*)(K8T + (size_t)row * NN + t * 16) = ov;
}

// Kernel A: finalize u (omega=1.25), then v~ row dots over K~T. grid (192, 4).
__global__ __launch_bounds__(256) void vrow_kernel(
    const unsigned char* __restrict__ K8T, const float* __restrict__ usumR,
    float* __restrict__ usumZ, const float* __restrict__ uR,
    float* __restrict__ uW, float* __restrict__ uF, float* __restrict__ vB,
    const int* __restrict__ ncG, int* __restrict__ ncS, int force) {
  const int b = blockIdx.y, bx = blockIdx.x;
  const int t = threadIdx.x, l = t & 63, wv = t >> 6;
  if (bx == 0 && t == 0) ncS[b] = 0;  // pre-gate zero (sticky-done)
  if (ncG[b] == 0) return;
  __shared__ __align__(16) float uS[NN];
  int flag = force;
#pragma unroll
  for (int jj = 0; jj < 16; ++jj) {
    int i = jj * 256 + t;
    float us = usumR[b * NN + i];
    float uo = uR[b * NN + i];
    float ut = A_VAL / us;
    float r = ut / uo;
    float un = uo * r * sqrtf(sqrtf(r));  // r^1.25
    uS[i] = un;
    if (bx == 0) {
      uW[b * NN + i] = un;
      uF[b * NN + i] = un;
      if (fabsf(ut - uo) > EPS_CONV * uo) flag = 1;
    }
    if (bx == 1) usumZ[b * NN + i] = 0.f;
  }
  __syncthreads();
  if (bx == 0 && flag) ncS[b] = 1;  // ordered after t0's zero by the barrier
  const unsigned char* KTb = K8T + (size_t)(b * NM + bx * 12) * NN;
#pragma unroll 1
  for (int rr = 0; rr < 3; ++rr) {
    int row = wv * 3 + rr;  // 0..11
    const unsigned int* Kp = (const unsigned int*)(KTb + (size_t)row * NN);
    float s = 0.f;
#pragma unroll
    for (int p = 0; p < 16; ++p) {
      unsigned int q = Kp[l + 64 * p];
      float4 d;
      dec4(q, d);
      float4 uu = ((const float4*)uS)[l + 64 * p];
      s += d.x * uu.x + d.y * uu.y + d.z * uu.z + d.w * uu.w;
    }
    s = waveSum(s);
    if (l == 0) vB[b * NM + bx * 12 + row] = B_VAL / s;
  }
}

// Kernel B: tiled column partials: usumA[n] += sum_m K~T[m][n]*v~[m].
// grid (16, 8, 4); 256 atomics/block.
__global__ __launch_bounds__(256) void ucol_kernel(
    const unsigned char* __restrict__ K8T, const float* __restrict__ vB,
    float* __restrict__ usumA, const int* __restrict__ ncG) {
  const int b = blockIdx.z;
  if (ncG[b] == 0) return;
  const int nch = blockIdx.x;  // 0..15 (256 n)
  const int mch = blockIdx.y;  // 0..7  (288 m)
  const int t = threadIdx.x, l = t & 63, wv = t >> 6;
  __shared__ float vS[288];
  __shared__ __align__(16) float red[4][64][4];
  for (int i = t; i < 288; i += 256) vS[i] = vB[b * NM + mch * 288 + i];
  __syncthreads();
  const unsigned char* Kp =
      K8T + (size_t)(b * NM + mch * 288) * NN + nch * 256 + l * 4;
  float4 acc = {0.f, 0.f, 0.f, 0.f};
#pragma unroll 8
  for (int i = 0; i < 72; ++i) {
    int m = i * 4 + wv;
    unsigned int q = *(const unsigned int*)(Kp + (size_t)m * NN);
    float4 d;
    dec4(q, d);
    float vv = vS[m];
    acc.x += d.x * vv;
    acc.y += d.y * vv;
    acc.z += d.z * vv;
    acc.w += d.w * vv;
  }
  *(float4*)red[wv][l] = acc;
  __syncthreads();
  if (wv == 0) {
    float4 a0 = *(float4*)red[0][l];
    float4 a1 = *(float4*)red[1][l];
    float4 a2 = *(float4*)red[2][l];
    float4 a3 = *(float4*)red[3][l];
    float* dst = usumA + (size_t)b * NN + nch * 256 + l * 4;
    atomicAdd(dst + 0, a0.x + a1.x + a2.x + a3.x);
    atomicAdd(dst + 1, a0.y + a1.y + a2.y + a3.y);
    atomicAdd(dst + 2, a0.z + a1.z + a2.z + a3.z);
    atomicAdd(dst + 3, a0.w + a1.w + a2.w + a3.w);
  }
}

// XT partial[kh] = v~[m]*umax[b]/S_Q * sum_n XquT[c][n]*K~T[m][n] via NATIVE
// bf8 MFMA. Split-K=2: grid (4, 36, 8). Tile 64c x 64m, BK=64.
__global__ __launch_bounds__(256) void xspace_bf8(
    const unsigned char* __restrict__ XquT, const unsigned char* __restrict__ K8T,
    const float* __restrict__ vB, const float* __restrict__ umax,
    float* __restrict__ XT0, float* __restrict__ XT1) {
  __shared__ __align__(16) unsigned char As[64][80];
  __shared__ __align__(16) unsigned char Bs[64][80];
  const int b = blockIdx.z & 3, kh = blockIdx.z >> 2;
  const int c0 = blockIdx.x * 64, m0 = blockIdx.y * 64;
  const int t = threadIdx.x, l = t & 63, w = t >> 6;
  const int wc = (w >> 1) * 32, wm = (w & 1) * 32;
  const int fr = l & 15, fq = l >> 4;
  f32x4 zero = {0.f, 0.f, 0.f, 0.f};
  f32x4 acc[2][2];
#pragma unroll
  for (int i = 0; i < 2; ++i)
#pragma unroll
    for (int j = 0; j < 2; ++j) acc[i][j] = zero;

  const int srow = t >> 2, sseg = t & 3;  // 64 rows x 4 x 16B
  const int kbeg = kh * 2048;
  for (int k0 = kbeg; k0 < kbeg + 2048; k0 += 64) {
    *(uint4*)&As[srow][sseg * 16] = *(const uint4*)(
        XquT + ((size_t)b * NC + c0 + srow) * NN + k0 + sseg * 16);
    *(uint4*)&Bs[srow][sseg * 16] = *(const uint4*)(
        K8T + ((size_t)b * NM + m0 + srow) * NN + k0 + sseg * 16);
    __syncthreads();
    long long a[2][2], bb[2][2];
#pragma unroll
    for (int f = 0; f < 2; ++f)
#pragma unroll
      for (int ks = 0; ks < 2; ++ks) {
        a[f][ks] = *(const long long*)&As[wc + f * 16 + fr][ks * 32 + fq * 8];
        bb[f][ks] = *(const long long*)&Bs[wm + f * 16 + fr][ks * 32 + fq * 8];
      }
#pragma unroll
    for (int ks = 0; ks < 2; ++ks)
#pragma unroll
      for (int i = 0; i < 2; ++i)
#pragma unroll
        for (int j = 0; j < 2; ++j)
          acc[i][j] = __builtin_amdgcn_mfma_f32_16x16x32_bf8_bf8(
              a[i][ks], bb[j][ks], acc[i][j], 0, 0, 0);
    __syncthreads();
  }
  const float sb = umax[b] * (1.0f / S_Q);
  float* XTo = kh ? XT1 : XT0;
#pragma unroll
  for (int fj = 0; fj < 2; ++fj) {
    int m = m0 + wm + fj * 16 + fr;
    float vm = vB[(size_t)b * NM + m] * sb;
#pragma unroll
    for (int fi = 0; fi < 2; ++fi) {
      int cb = c0 + wc + fi * 16 + fq * 4;
#pragma unroll
      for (int r = 0; r < 4; ++r)
        XTo[((size_t)b * NC + cb + r) * NM + m] = vm * acc[fi][fj][r];
    }
  }
}

// out_aligned = H + alpha*(XT0+XT1); out_feat = XT0+XT1; partial (H-XT)^2 sums
__global__ __launch_bounds__(256) void finalize_kernel(
    const float* __restrict__ H, const float* __restrict__ XT0,
    const float* __restrict__ XT1, float* __restrict__ out_aligned,
    float* __restrict__ out_feat, float* __restrict__ partials) {
  const int t = threadIdx.x;
  float s = 0.f;
  for (int i = blockIdx.x * 256 + t; i < OUT_ELEMS / 4; i += 1024 * 256) {
    float4 h = *(const float4*)(H + (size_t)i * 4);
    float4 xa = *(const float4*)(XT0 + (size_t)i * 4);
    float4 xb = *(const float4*)(XT1 + (size_t)i * 4);
    float4 x;
    x.x = xa.x + xb.x;
    x.y = xa.y + xb.y;
    x.z = xa.z + xb.z;
    x.w = xa.w + xb.w;
    float4 o;
    o.x = h.x + ALPHA_C * x.x;
    o.y = h.y + ALPHA_C * x.y;
    o.z = h.z + ALPHA_C * x.z;
    o.w = h.w + ALPHA_C * x.w;
    *(float4*)(out_aligned + (size_t)i * 4) = o;
    out_feat[(size_t)i * 4 + 0] = x.x;  // dest misaligned by 1 float -> scalar
    out_feat[(size_t)i * 4 + 1] = x.y;
    out_feat[(size_t)i * 4 + 2] = x.z;
    out_feat[(size_t)i * 4 + 3] = x.w;
    float dx = h.x - x.x, dy = h.y - x.y, dz = h.z - x.z, dw = h.w - x.w;
    s += dx * dx + dy * dy + dz * dz + dw * dw;
  }
  s = waveSum(s);
  __shared__ float ws_[4];
  if ((t & 63) == 0) ws_[t >> 6] = s;
  __syncthreads();
  if (t == 0) partials[blockIdx.x] = ws_[0] + ws_[1] + ws_[2] + ws_[3];
}

__global__ __launch_bounds__(256) void lot_kernel(
    const float* __restrict__ partials, float* __restrict__ out_lot) {
  float s = 0.f;
  for (int i = threadIdx.x; i < 1024; i += 256) s += partials[i];
  s = waveSum(s);
  __shared__ float ws_[4];
  if ((threadIdx.x & 63) == 0) ws_[threadIdx.x >> 6] = s;
  __syncthreads();
  if (threadIdx.x == 0)
    out_lot[0] = (ws_[0] + ws_[1] + ws_[2] + ws_[3]) / (float)OUT_ELEMS;
}

extern "C" void kernel_launch(void* const* d_in, const int* in_sizes, int n_in,
                              void* d_out, int out_size, void* d_ws,
                              size_t ws_size, hipStream_t stream) {
  const float* X = (const float*)d_in[0];  // sc (4096,256)
  const float* H = (const float*)d_in[1];  // h_spot (4,256,48,48)
  float* out = (float*)d_out;
  char* ws = (char*)d_ws;

  // workspace layout (bytes)
  unsigned short* KT = (unsigned short*)(ws);           // 75,497,472 (dead after requant1)
  unsigned char* XquT = (unsigned char*)(ws);           // 4,194,304 (aliases KT; post-loop)
  unsigned char* K8T = (unsigned char*)(ws + 75497472); // 37,748,736 (fp8: loop + xspace)
  float* XT0 = (float*)(ws + 113246208);                // 9,437,184
  // aliases inside XT0 region (dead before xspace writes):
  unsigned short* Xbf = (unsigned short*)(ws + 113246208);           // 2,097,152
  unsigned short* HT = (unsigned short*)(ws + 113246208 + 2097152);  // 4,718,592
  float* usum = (float*)(ws + 122683392);   // 2 slots x 65,536
  float* u = (float*)(ws + 122814464);      // 2 slots x 65,536
  float* uF = (float*)(ws + 122945536);     // 65,536
  float* vB = (float*)(ws + 123011072);     // 36,864
  float* x2 = (float*)(ws + 123047936);     // 16,384
  float* y2 = (float*)(ws + 123064320);     // 36,864
  int* nc = (int*)(ws + 123101184);         // 32
  float* partials = (float*)(ws + 123101216);  // 4,096
  float* umax = (float*)(ws + 123105312);   // 16
  float* XT1 = (float*)(ws + 134217728);    // 9,437,184 -> ends 143,654,912
  if (ws_size < (size_t)143654912) return;

  x2_kernel<<<1024, 256, 0, stream>>>(X, x2);
  y2_kernel<<<dim3(72, 4), 256, 0, stream>>>(H, y2);
  prep_xbf<<<1024, 256, 0, stream>>>(X, Xbf);
  prep_ht<<<dim3(72, 8, 4), 256, 0, stream>>>(H, HT);
  cost_k_mfma<<<dim3(32, 18, 4), 256, 0, stream>>>(Xbf, HT, x2, y2, KT);
  requant_kernel<<<9216, 256, 0, stream>>>(KT, K8T);
  init_kernel<<<64, 256, 0, stream>>>(usum, u, nc);
  for (int it = 0; it < MAX_IT; ++it) {
    const int p = it & 1, q = 1 - p;
    vrow_kernel<<<dim3(192, 4), 256, 0, stream>>>(
        K8T, usum + (size_t)p * 4 * NN, usum + (size_t)q * 4 * NN,
        u + (size_t)p * 4 * NN, u + (size_t)q * 4 * NN, uF, vB,
        nc + q * 4, nc + p * 4, it == 0 ? 1 : 0);
    ucol_kernel<<<dim3(16, 8, 4), 256, 0, stream>>>(
        K8T, vB, usum + (size_t)q * 4 * NN, nc + q * 4);
  }
  umax_kernel<<<4, 256, 0, stream>>>(uF, umax);
  prep_xqu<<<dim3(128, 8, 4), 256, 0, stream>>>(X, uF, umax, XquT);
  xspace_bf8<<<dim3(4, 36, 8), 256, 0, stream>>>(XquT, K8T, vB, umax, XT0, XT1);
  finalize_kernel<<<1024, 256, 0, stream>>>(H, XT0, XT1, out,
                                            out + OUT_ELEMS + 1, partials);
  lot_kernel<<<1, 256, 0, stream>>>(partials, out + OUT_ELEMS);
}